// Round 15
// baseline (370.001 us; speedup 1.0000x reference)
//
#include <hip/hip_runtime.h>
#include <math.h>

typedef __attribute__((ext_vector_type(8))) short short8;
typedef __attribute__((ext_vector_type(8))) unsigned short ushort8;
typedef __attribute__((ext_vector_type(4))) unsigned short us4;
typedef __attribute__((ext_vector_type(4))) unsigned int u32x4;
typedef __attribute__((ext_vector_type(4))) float f32x4;

#define NH 16
#define HD 64
#define SEQ 1024
#define NB 8
#define CH 1024
#define TD 256
#define GROW 1025      // flat row stride of G' (the skew trick)
#define RSTRIDE 132232 // private region stride: 129*1025=132225 padded to mult-of-8
#define LOG2E 1.4426950408889634f

__device__ __forceinline__ unsigned short f2bf(float f) {
  union { float f; unsigned int u; } v; v.f = f;
  unsigned int r = v.u + 0x7FFFu + ((v.u >> 16) & 1u);
  return (unsigned short)(r >> 16);
}
__device__ __forceinline__ float bf2f(unsigned short s) {
  union { unsigned int u; float f; } v; v.u = ((unsigned int)s) << 16;
  return v.f;
}
__device__ __forceinline__ float hexp2(float x) {
  float r;
  asm("v_exp_f32 %0, %1" : "=v"(r) : "v"(x));
  return r;
}
__device__ __forceinline__ void gload_lds16(const unsigned short* g, unsigned short* l) {
  __builtin_amdgcn_global_load_lds(
      (const __attribute__((address_space(1))) unsigned int*)g,
      (__attribute__((address_space(3))) unsigned int*)l, 16, 0, 0);
}

// ---------------- time projection (fp32) ----------------
__global__ __launch_bounds__(256) void time_proj_kernel(
    const float* __restrict__ time_emb, const float* __restrict__ W_time,
    const float* __restrict__ b_time, float* __restrict__ tqkv) {
  int idx = blockIdx.x * 256 + threadIdx.x;
  if (idx >= NB * 3072) return;
  int b = idx / 3072, c = idx % 3072;
  float s = b_time[c];
  for (int t = 0; t < TD; ++t) s += time_emb[b * TD + t] * W_time[t * 3072 + c];
  tqkv[idx] = s;
}

// ---------------- Er fp32 -> bf16, scaled by log2e ----------------
__global__ __launch_bounds__(256) void er_convert_kernel(
    const float* __restrict__ Er, unsigned short* __restrict__ Er_bf) {
  int i = blockIdx.x * 256 + threadIdx.x;
  if (i < SEQ * HD) Er_bf[i] = f2bf(Er[i] * LOG2E);
}

// ---------------- fp32 -> bf16 vector convert ----------------
__global__ __launch_bounds__(256) void convert_bf_kernel(
    const float* __restrict__ in, unsigned short* __restrict__ out, int n8) {
  int i = blockIdx.x * 256 + threadIdx.x;
  if (i >= n8) return;
  float4 a = ((const float4*)in)[2 * i];
  float4 b = ((const float4*)in)[2 * i + 1];
  ushort8 o;
  o[0] = f2bf(a.x); o[1] = f2bf(a.y); o[2] = f2bf(a.z); o[3] = f2bf(a.w);
  o[4] = f2bf(b.x); o[5] = f2bf(b.y); o[6] = f2bf(b.z); o[7] = f2bf(b.w);
  ((ushort8*)out)[i] = o;
}

// ---------------- fp32 W[R][C] -> bf16 Wt[C][R] ----------------
__global__ __launch_bounds__(256) void transpose_bf_kernel(
    const float* __restrict__ W, unsigned short* __restrict__ Wt, int R, int Cc) {
  __shared__ float T[64][65];
  int r0 = blockIdx.y * 64, c0 = blockIdx.x * 64;
  for (int idx = threadIdx.x; idx < 4096; idx += 256) {
    int r = idx >> 6, c = idx & 63;
    T[r][c] = W[(size_t)(r0 + r) * Cc + c0 + c];
  }
  __syncthreads();
  for (int idx = threadIdx.x; idx < 4096; idx += 256) {
    int c = idx >> 6, r = idx & 63;
    Wt[(size_t)(c0 + c) * R + r0 + r] = f2bf(T[r][c]);
  }
}

// ---------------- QKV GEMM: bf16 MFMA, WHICH-specialized epilogue ----------------
template <int WHICH>
__global__ __launch_bounds__(256) void qkv_gemm_w(
    const unsigned short* __restrict__ A, const unsigned short* __restrict__ Bt,
    const float* __restrict__ bq, const float* __restrict__ tq,
    unsigned short* __restrict__ dst) {
  __shared__ unsigned short As[128 * 32];
  __shared__ unsigned short Bs[128 * 32];
  const int m0 = blockIdx.x * 128, n0 = blockIdx.y * 128;
  const int tid = threadIdx.x, l = tid & 63, w = tid >> 6;
  const int wm = w >> 1, wn = w & 1;
  const int grp = l >> 4, col = l & 15;
  f32x4 acc[4][4];
#pragma unroll
  for (int mi = 0; mi < 4; ++mi)
#pragma unroll
    for (int ni = 0; ni < 4; ++ni) acc[mi][ni] = (f32x4){0.f, 0.f, 0.f, 0.f};

  for (int k0 = 0; k0 < 1024; k0 += 32) {
    __syncthreads();
#pragma unroll
    for (int i = 0; i < 2; ++i) {
      int seg = i * 256 + w * 64 + l;
      int mr = seg >> 2, kq = seg & 3;
      gload_lds16(A + (size_t)(m0 + mr) * 1024 + k0 + kq * 8,
                  &As[(i * 256 + w * 64) * 8]);
      gload_lds16(Bt + (size_t)(n0 + mr) * 1024 + k0 + kq * 8,
                  &Bs[(i * 256 + w * 64) * 8]);
    }
    __syncthreads();
    short8 af[4], bfv[4];
#pragma unroll
    for (int mi = 0; mi < 4; ++mi)
      af[mi] = *(const short8*)&As[(wm * 64 + mi * 16 + col) * 32 + grp * 8];
#pragma unroll
    for (int ni = 0; ni < 4; ++ni)
      bfv[ni] = *(const short8*)&Bs[(wn * 64 + ni * 16 + col) * 32 + grp * 8];
#pragma unroll
    for (int mi = 0; mi < 4; ++mi)
#pragma unroll
      for (int ni = 0; ni < 4; ++ni)
        acc[mi][ni] = __builtin_amdgcn_mfma_f32_16x16x32_bf16(af[mi], bfv[ni], acc[mi][ni], 0, 0, 0);
  }

  const int bidx = m0 >> 10;
  float biasv[4];
  int hhv[4], dv[4];
#pragma unroll
  for (int ni = 0; ni < 4; ++ni) {
    int c2 = n0 + wn * 64 + ni * 16 + col;
    biasv[ni] = bq[c2] + tq[bidx * 3072 + c2];
    hhv[ni] = c2 >> 6;
    dv[ni] = c2 & 63;
  }
  if (WHICH == 2) {
    int t = (m0 & 1023) + wm * 64;
#pragma unroll
    for (int ni = 0; ni < 4; ++ni) {
      size_t rowb = ((size_t)(bidx * 16 + hhv[ni]) * 64 + dv[ni]) * 1024;
      int swz = (dv[ni] & 7) << 3;
#pragma unroll
      for (int rr = 0; rr < 4; ++rr) {
        int kbase = (grp * 4 + rr) * 4;
        int colix = t + ((kbase & ~7) ^ swz) + (kbase & 7);
        us4 pk;
#pragma unroll
        for (int mi = 0; mi < 4; ++mi) pk[mi] = f2bf(acc[mi][ni][rr] + biasv[ni]);
        *(us4*)&dst[rowb + colix] = pk;
      }
    }
  } else if (WHICH == 1) {
#pragma unroll
    for (int mi = 0; mi < 4; ++mi)
#pragma unroll
      for (int rr = 0; rr < 4; ++rr) {
        int nn = (m0 + wm * 64 + mi * 16 + grp * 4 + rr) & 1023;
#pragma unroll
        for (int ni = 0; ni < 4; ++ni) {
          size_t bhh = (size_t)(bidx * 16 + hhv[ni]);
          dst[(bhh * 1024 + nn) * 64 + (dv[ni] ^ ((nn & 7) << 3))] =
              f2bf(acc[mi][ni][rr] + biasv[ni]);
        }
      }
  } else {
#pragma unroll
    for (int mi = 0; mi < 4; ++mi)
#pragma unroll
      for (int rr = 0; rr < 4; ++rr) {
        int nn = (m0 + wm * 64 + mi * 16 + grp * 4 + rr) & 1023;
#pragma unroll
        for (int ni = 0; ni < 4; ++ni) {
          size_t bhh = (size_t)(bidx * 16 + hhv[ni]);
          dst[(bhh * 1024 + nn) * 64 + dv[ni]] = f2bf(acc[mi][ni][rr] + biasv[ni]);
        }
      }
  }
}

// ---------------- output projection: bf16 MFMA ----------------
__global__ __launch_bounds__(256) void out_gemm_mfma(
    const unsigned short* __restrict__ A, const unsigned short* __restrict__ Bt,
    const float* __restrict__ bias, float* __restrict__ out) {
  __shared__ unsigned short As[128 * 32];
  __shared__ unsigned short Bs[128 * 32];
  const int m0 = blockIdx.x * 128, n0 = blockIdx.y * 128;
  const int tid = threadIdx.x, l = tid & 63, w = tid >> 6;
  const int wm = w >> 1, wn = w & 1;
  const int grp = l >> 4, col = l & 15;
  f32x4 acc[4][4];
#pragma unroll
  for (int mi = 0; mi < 4; ++mi)
#pragma unroll
    for (int ni = 0; ni < 4; ++ni) acc[mi][ni] = (f32x4){0.f, 0.f, 0.f, 0.f};

  for (int k0 = 0; k0 < 1024; k0 += 32) {
    __syncthreads();
#pragma unroll
    for (int i = 0; i < 2; ++i) {
      int seg = i * 256 + w * 64 + l;
      int mr = seg >> 2, kq = seg & 3;
      gload_lds16(A + (size_t)(m0 + mr) * 1024 + k0 + kq * 8,
                  &As[(i * 256 + w * 64) * 8]);
      gload_lds16(Bt + (size_t)(n0 + mr) * 1024 + k0 + kq * 8,
                  &Bs[(i * 256 + w * 64) * 8]);
    }
    __syncthreads();
    short8 af[4], bfv[4];
#pragma unroll
    for (int mi = 0; mi < 4; ++mi)
      af[mi] = *(const short8*)&As[(wm * 64 + mi * 16 + col) * 32 + grp * 8];
#pragma unroll
    for (int ni = 0; ni < 4; ++ni)
      bfv[ni] = *(const short8*)&Bs[(wn * 64 + ni * 16 + col) * 32 + grp * 8];
#pragma unroll
    for (int mi = 0; mi < 4; ++mi)
#pragma unroll
      for (int ni = 0; ni < 4; ++ni)
        acc[mi][ni] = __builtin_amdgcn_mfma_f32_16x16x32_bf16(af[mi], bfv[ni], acc[mi][ni], 0, 0, 0);
  }
  float bv[4];
#pragma unroll
  for (int ni = 0; ni < 4; ++ni) bv[ni] = bias[n0 + wn * 64 + ni * 16 + col];
#pragma unroll
  for (int mi = 0; mi < 4; ++mi)
#pragma unroll
    for (int rr = 0; rr < 4; ++rr) {
      int row = m0 + wm * 64 + mi * 16 + grp * 4 + rr;
#pragma unroll
      for (int ni = 0; ni < 4; ++ni) {
        int c = n0 + wn * 64 + ni * 16 + col;
        out[(size_t)row * 1024 + c] = acc[mi][ni][rr] + bv[ni];
      }
    }
}

// ---------------- flash attention with fused G' prologue ----------------
// Prologue: block computes its private skewed-rel rows G'[n][j] = q_n . Er'[j]
// for n in [n0, n0+128] INCLUSIVE (row n0+127's flat band crosses into row n0+128)
// into Gpriv (129 rows, stride GROW, region stride RSTRIDE). Writes go through the
// block's own L2 and are re-read by the SAME block -> no HBM round-trip (g_gemm2's
// 134 MB/slab write+read at HBM was 72 us total). barrier after prologue drains vmcnt.
// Main loop: QBLK=128, swapped MFMA operands, P overlaid on Band rows (wave-private),
// barrier A before the async Band overwrite (r12/13 lesson), exact rescale.
__global__ __launch_bounds__(256) void attn_kernel(
    const unsigned short* __restrict__ qb, const unsigned short* __restrict__ ksw,
    const unsigned short* __restrict__ vtsw, const unsigned short* __restrict__ Er_bf,
    unsigned short* __restrict__ Gp, unsigned short* __restrict__ attn_o, int bh_base) {
  __shared__ __align__(16) unsigned short KsL[2][4096];
  __shared__ __align__(16) unsigned short VtL[2][4096];
  __shared__ __align__(16) unsigned short BandP[128][72];  // Band ∪ P (wave-private rows)

  const int wg = blockIdx.x + 8 * blockIdx.y;
  const int chunk = gridDim.y;  // nwg/8
  const int nid = (wg & 7) * chunk + (wg >> 3);
  const int bhl = nid >> 3;
  const int n0 = (nid & 7) * 128;
  const int bh = bh_base + bhl;
  const int b = bh >> 4, h = bh & 15;
  const int tid = threadIdx.x, lane = tid & 63, wq = tid >> 6;
  const int grp = lane >> 4, col = lane & 15;

  short8 aq[2][2];
#pragma unroll
  for (int nf = 0; nf < 2; ++nf)
#pragma unroll
    for (int dc = 0; dc < 2; ++dc)
      aq[nf][dc] = *(const short8*)(qb + ((size_t)(bh * SEQ + n0 + wq * 32 + nf * 16 + col)) * HD + dc * 32 + grp * 8);

  unsigned short* Gpriv = Gp + (size_t)wg * RSTRIDE;

  // ---- prologue: G' rows [0,129) of this block ----
  {
    short8 aq_e[2];  // extra fragment rows n0+128+col (last tile: garbage, never read)
#pragma unroll
    for (int dc = 0; dc < 2; ++dc)
      aq_e[dc] = *(const short8*)(qb + ((size_t)bh * SEQ + n0 + 128 + col) * HD + dc * 32 + grp * 8);
    for (int jt = 0; jt < 16; ++jt) {
      f32x4 ag[2][4], ae[4];
#pragma unroll
      for (int cf = 0; cf < 4; ++cf) {
        ag[0][cf] = (f32x4){0.f, 0.f, 0.f, 0.f};
        ag[1][cf] = (f32x4){0.f, 0.f, 0.f, 0.f};
        ae[cf] = (f32x4){0.f, 0.f, 0.f, 0.f};
      }
      const bool mine = (jt >> 2) == wq;  // wave's j-quarter handles the extra row
#pragma unroll
      for (int cf = 0; cf < 4; ++cf)
#pragma unroll
        for (int dc = 0; dc < 2; ++dc) {
          short8 er = *(const short8*)(Er_bf + (size_t)(jt * 64 + cf * 16 + col) * 64 + dc * 32 + grp * 8);
          ag[0][cf] = __builtin_amdgcn_mfma_f32_16x16x32_bf16(aq[0][dc], er, ag[0][cf], 0, 0, 0);
          ag[1][cf] = __builtin_amdgcn_mfma_f32_16x16x32_bf16(aq[1][dc], er, ag[1][cf], 0, 0, 0);
          if (mine) ae[cf] = __builtin_amdgcn_mfma_f32_16x16x32_bf16(aq_e[dc], er, ae[cf], 0, 0, 0);
        }
#pragma unroll
      for (int nf = 0; nf < 2; ++nf)
#pragma unroll
        for (int cf = 0; cf < 4; ++cf)
#pragma unroll
          for (int rr = 0; rr < 4; ++rr)
            Gpriv[(size_t)(wq * 32 + nf * 16 + grp * 4 + rr) * GROW + jt * 64 + cf * 16 + col] =
                f2bf(ag[nf][cf][rr]);
      if (mine && grp == 0)
#pragma unroll
        for (int cf = 0; cf < 4; ++cf)
          Gpriv[(size_t)128 * GROW + jt * 64 + cf * 16 + col] = f2bf(ae[cf][0]);
    }
    if (lane < 32) Gpriv[(size_t)(wq * 32 + lane) * GROW + 1024] = 0;  // skew hole
  }
  __syncthreads();  // vmcnt(0)+lgkmcnt(0) drain: G' writes visible before Band loads

  f32x4 acco[2][4];
#pragma unroll
  for (int nf = 0; nf < 2; ++nf)
#pragma unroll
    for (int oc = 0; oc < 4; ++oc) acco[nf][oc] = (f32x4){0.f, 0.f, 0.f, 0.f};
  float mrun[2] = {-INFINITY, -INFINITY}, lrun[2] = {0.f, 0.f};

  const float scale2 = 0.125f * LOG2E;
  const unsigned short* kbh = ksw + (size_t)bh * SEQ * HD;
  const unsigned short* vbh = vtsw + (size_t)bh * HD * SEQ;
  const unsigned short* gbase = Gpriv + (1016 - n0);

  auto STAGE_KV = [&](int buf, int m0) {
#pragma unroll
    for (int i = 0; i < 2; ++i) {
      int gi = i * 256 + wq * 64 + lane;
      int row = gi >> 3, gc = gi & 7;
      gload_lds16(kbh + (((size_t)(m0 + row)) << 6) + gc * 8,
                  &KsL[buf][(i * 256 + wq * 64) * 8]);
      gload_lds16(vbh + (((size_t)row) << 10) + m0 + gc * 8,
                  &VtL[buf][(i * 256 + wq * 64) * 8]);
    }
  };
  auto STAGE_BAND = [&](int m0) {  // wave wq stages its own rows [wq*32, +32)
    const unsigned short* gsrc = gbase + m0;
    unsigned short* bdst = &BandP[0][0];
    const int g0 = wq * 288;
#pragma unroll
    for (int it = 0; it < 4; ++it) {
      int g = g0 + it * 64 + lane;
      int r = g / 9, seg = g - r * 9;
      gload_lds16(gsrc + r * 1024 + seg * 8, bdst + g * 8);
    }
    if (lane < 32) {
      int g = g0 + 256 + lane;
      int r = g / 9, seg = g - r * 9;
      gload_lds16(gsrc + r * 1024 + seg * 8, bdst + g * 8);
    }
  };

  STAGE_KV(0, 0);
  STAGE_BAND(0);
  __syncthreads();

  for (int t = 0; t < 16; ++t) {
    const int cur = t & 1;
    if (t < 15) STAGE_KV(cur ^ 1, (t + 1) * 64);
    // QK^T swapped
    f32x4 acc[2][4];
#pragma unroll
    for (int nf = 0; nf < 2; ++nf)
#pragma unroll
      for (int mc = 0; mc < 4; ++mc) acc[nf][mc] = (f32x4){0.f, 0.f, 0.f, 0.f};
    __builtin_amdgcn_s_setprio(1);
#pragma unroll
    for (int mc = 0; mc < 4; ++mc)
#pragma unroll
      for (int dc = 0; dc < 2; ++dc) {
        short8 bk = *(const short8*)&KsL[cur][(mc * 16 + col) * 64 + (((dc * 4 + grp) ^ (col & 7)) << 3)];
#pragma unroll
        for (int nf = 0; nf < 2; ++nf)
          acc[nf][mc] = __builtin_amdgcn_mfma_f32_16x16x32_bf16(bk, aq[nf][dc], acc[nf][mc], 0, 0, 0);
      }
    __builtin_amdgcn_s_setprio(0);
    // lane-local online softmax (log2 domain, EXACT rescale); P overwrites Band row
#pragma unroll
    for (int nf = 0; nf < 2; ++nf) {
      const int dr = wq * 32 + nf * 16 + col;
      float s[4][4];
#pragma unroll
      for (int mc = 0; mc < 4; ++mc)
#pragma unroll
        for (int r = 0; r < 4; ++r)
          s[mc][r] = fmaf(acc[nf][mc][r], scale2, bf2f(BandP[dr][7 + mc * 16 + grp * 4 + r]));
      float mx = s[0][0];
#pragma unroll
      for (int mc = 0; mc < 4; ++mc)
#pragma unroll
        for (int r = 0; r < 4; ++r) mx = fmaxf(mx, s[mc][r]);
      mx = fmaxf(mx, __shfl_xor(mx, 16));
      mx = fmaxf(mx, __shfl_xor(mx, 32));
      if (mx > mrun[nf]) {  // exact: keep P <= 1 (bf16 precision budget)
        float cr = hexp2(mrun[nf] - mx);
        mrun[nf] = mx;
        lrun[nf] *= cr;
#pragma unroll
        for (int oc = 0; oc < 4; ++oc)
#pragma unroll
          for (int r = 0; r < 4; ++r) acco[nf][oc][r] *= cr;
      }
      float p[4][4];
#pragma unroll
      for (int mc = 0; mc < 4; ++mc)
#pragma unroll
        for (int r = 0; r < 4; ++r) {
          p[mc][r] = hexp2(s[mc][r] - mrun[nf]);
          lrun[nf] += p[mc][r];
        }
      unsigned int wpk[8];
#pragma unroll
      for (int r = 0; r < 4; ++r)
#pragma unroll
        for (int mh = 0; mh < 2; ++mh)
          asm("v_cvt_pk_bf16_f32 %0, %1, %2"
              : "=v"(wpk[r * 2 + mh]) : "v"(p[mh * 2][r]), "v"(p[mh * 2 + 1][r]));
      *(u32x4*)&BandP[dr][grp * 16] = (u32x4){wpk[0], wpk[1], wpk[2], wpk[3]};
      *(u32x4*)&BandP[dr][grp * 16 + 8] = (u32x4){wpk[4], wpk[5], wpk[6], wpk[7]};
    }
    // hoist ap fragments to regs (same-wave DS, safe without barrier)
    short8 ap[2][2];
#pragma unroll
    for (int nf = 0; nf < 2; ++nf)
#pragma unroll
      for (int kc = 0; kc < 2; ++kc)
        ap[nf][kc] = *(const short8*)&BandP[wq * 32 + nf * 16 + col][kc * 32 + grp * 8];
    __syncthreads();  // A: DS drain — all BandP reads done before async overwrite
    if (t < 15) STAGE_BAND((t + 1) * 64);  // latency hides under PV
    // PV swapped (sigma k-order on both operands)
    __builtin_amdgcn_s_setprio(1);
#pragma unroll
    for (int oc = 0; oc < 4; ++oc)
#pragma unroll
      for (int kc = 0; kc < 2; ++kc) {
        short8 bv = *(const short8*)&VtL[cur][(oc * 16 + col) * 64 + (((kc * 4 + grp) ^ (col & 7)) << 3)];
#pragma unroll
        for (int nf = 0; nf < 2; ++nf)
          acco[nf][oc] = __builtin_amdgcn_mfma_f32_16x16x32_bf16(bv, ap[nf][kc], acco[nf][oc], 0, 0, 0);
      }
    __builtin_amdgcn_s_setprio(0);
    __syncthreads();  // B: drains KV + Band prefetches; protects buf reuse
  }
  // epilogue
#pragma unroll
  for (int nf = 0; nf < 2; ++nf) {
    float tot = lrun[nf];
    tot += __shfl_xor(tot, 16);
    tot += __shfl_xor(tot, 32);
    float inv = 1.0f / tot;
    const int n = n0 + wq * 32 + nf * 16 + col;
#pragma unroll
    for (int oc = 0; oc < 4; ++oc) {
      us4 pk;
#pragma unroll
      for (int r = 0; r < 4; ++r) pk[r] = f2bf(acco[nf][oc][r] * inv);
      *(us4*)&attn_o[((size_t)(b * SEQ + n)) * CH + h * HD + oc * 16 + grp * 4] = pk;
    }
  }
}

extern "C" void kernel_launch(void* const* d_in, const int* in_sizes, int n_in,
                              void* d_out, int out_size, void* d_ws, size_t ws_size,
                              hipStream_t stream) {
  const float* x        = (const float*)d_in[0];
  const float* time_emb = (const float*)d_in[1];
  const float* W_qkv    = (const float*)d_in[2];
  const float* b_qkv    = (const float*)d_in[3];
  const float* W_time   = (const float*)d_in[4];
  const float* b_time   = (const float*)d_in[5];
  const float* W_out    = (const float*)d_in[6];
  const float* b_out    = (const float*)d_in[7];
  const float* Er       = (const float*)d_in[8];
  float* out = (float*)d_out;

  char* p = (char*)d_ws;
  float* tqkv = (float*)p;                      p += 98304;
  unsigned short* qb = (unsigned short*)p;      p += 16777216;
  unsigned short* ksw = (unsigned short*)p;     p += 16777216;
  unsigned short* vtsw = (unsigned short*)p;    p += 16777216;
  unsigned short* attn_o = (unsigned short*)p;  p += 16777216;
  unsigned short* Er_bf = (unsigned short*)p;   p += 131072;
  unsigned short* Wout_t = (unsigned short*)p;  p += 2097152;
  unsigned short* x_bf = (unsigned short*)p;               // 16 MB (prep, then dead)
  unsigned short* Wqkv_t = x_bf + (size_t)8388608;         // 6 MB (prep, then dead)
  unsigned short* Gp = (unsigned short*)p;                 // per-block private G' regions

  size_t fixed = (size_t)(p - (char*)d_ws);
  // slab=64 needs 512 regions (135.4 MB); fallback slab=32 (256 regions)
  int slab_bh = (ws_size >= fixed + (size_t)512 * RSTRIDE * 2) ? 64 : 32;
  int nslab = 128 / slab_bh;

  er_convert_kernel<<<256, 256, 0, stream>>>(Er, Er_bf);
  time_proj_kernel<<<96, 256, 0, stream>>>(time_emb, W_time, b_time, tqkv);
  convert_bf_kernel<<<4096, 256, 0, stream>>>(x, x_bf, 1048576);
  transpose_bf_kernel<<<dim3(48, 16), 256, 0, stream>>>(W_qkv, Wqkv_t, 1024, 3072);
  transpose_bf_kernel<<<dim3(16, 16), 256, 0, stream>>>(W_out, Wout_t, 1024, 1024);
  qkv_gemm_w<0><<<dim3(64, 8), 256, 0, stream>>>(x_bf, Wqkv_t, b_qkv, tqkv, qb);
  qkv_gemm_w<1><<<dim3(64, 8), 256, 0, stream>>>(x_bf, Wqkv_t + (size_t)1048576,
                                                 b_qkv + 1024, tqkv + 1024, ksw);
  qkv_gemm_w<2><<<dim3(64, 8), 256, 0, stream>>>(x_bf, Wqkv_t + (size_t)2097152,
                                                 b_qkv + 2048, tqkv + 2048, vtsw);
  for (int s = 0; s < nslab; ++s) {
    attn_kernel<<<dim3(8, slab_bh), 256, 0, stream>>>(qb, ksw, vtsw, Er_bf, Gp,
                                                      attn_o, s * slab_bh);
  }
  out_gemm_mfma<<<dim3(64, 8), 256, 0, stream>>>(attn_o, Wout_t, b_out, out);
}

// Round 16
// 366.160 us; speedup vs baseline: 1.0105x; 1.0105x over previous
//
#include <hip/hip_runtime.h>
#include <math.h>

typedef __attribute__((ext_vector_type(8))) short short8;
typedef __attribute__((ext_vector_type(8))) unsigned short ushort8;
typedef __attribute__((ext_vector_type(4))) unsigned short us4;
typedef __attribute__((ext_vector_type(4))) unsigned int u32x4;
typedef __attribute__((ext_vector_type(4))) float f32x4;

#define NH 16
#define HD 64
#define SEQ 1024
#define NB 8
#define CH 1024
#define TD 256
#define GROW 1025  // flat row stride of G' (the skew trick)
#define LOG2E 1.4426950408889634f

__device__ __forceinline__ unsigned short f2bf(float f) {
  union { float f; unsigned int u; } v; v.f = f;
  unsigned int r = v.u + 0x7FFFu + ((v.u >> 16) & 1u);
  return (unsigned short)(r >> 16);
}
__device__ __forceinline__ float bf2f(unsigned short s) {
  union { unsigned int u; float f; } v; v.u = ((unsigned int)s) << 16;
  return v.f;
}
__device__ __forceinline__ float hexp2(float x) {
  float r;
  asm("v_exp_f32 %0, %1" : "=v"(r) : "v"(x));
  return r;
}
__device__ __forceinline__ void gload_lds16(const unsigned short* g, unsigned short* l) {
  __builtin_amdgcn_global_load_lds(
      (const __attribute__((address_space(1))) unsigned int*)g,
      (__attribute__((address_space(3))) unsigned int*)l, 16, 0, 0);
}

// ---------------- time projection (fp32) ----------------
__global__ __launch_bounds__(256) void time_proj_kernel(
    const float* __restrict__ time_emb, const float* __restrict__ W_time,
    const float* __restrict__ b_time, float* __restrict__ tqkv) {
  int idx = blockIdx.x * 256 + threadIdx.x;
  if (idx >= NB * 3072) return;
  int b = idx / 3072, c = idx % 3072;
  float s = b_time[c];
  for (int t = 0; t < TD; ++t) s += time_emb[b * TD + t] * W_time[t * 3072 + c];
  tqkv[idx] = s;
}

// ---------------- Er fp32 -> bf16, scaled by log2e ----------------
__global__ __launch_bounds__(256) void er_convert_kernel(
    const float* __restrict__ Er, unsigned short* __restrict__ Er_bf) {
  int i = blockIdx.x * 256 + threadIdx.x;
  if (i < SEQ * HD) Er_bf[i] = f2bf(Er[i] * LOG2E);
}

// ---------------- fp32 -> bf16 vector convert ----------------
__global__ __launch_bounds__(256) void convert_bf_kernel(
    const float* __restrict__ in, unsigned short* __restrict__ out, int n8) {
  int i = blockIdx.x * 256 + threadIdx.x;
  if (i >= n8) return;
  float4 a = ((const float4*)in)[2 * i];
  float4 b = ((const float4*)in)[2 * i + 1];
  ushort8 o;
  o[0] = f2bf(a.x); o[1] = f2bf(a.y); o[2] = f2bf(a.z); o[3] = f2bf(a.w);
  o[4] = f2bf(b.x); o[5] = f2bf(b.y); o[6] = f2bf(b.z); o[7] = f2bf(b.w);
  ((ushort8*)out)[i] = o;
}

// ---------------- fp32 W[R][C] -> bf16 Wt[C][R] ----------------
__global__ __launch_bounds__(256) void transpose_bf_kernel(
    const float* __restrict__ W, unsigned short* __restrict__ Wt, int R, int Cc) {
  __shared__ float T[64][65];
  int r0 = blockIdx.y * 64, c0 = blockIdx.x * 64;
  for (int idx = threadIdx.x; idx < 4096; idx += 256) {
    int r = idx >> 6, c = idx & 63;
    T[r][c] = W[(size_t)(r0 + r) * Cc + c0 + c];
  }
  __syncthreads();
  for (int idx = threadIdx.x; idx < 4096; idx += 256) {
    int c = idx >> 6, r = idx & 63;
    Wt[(size_t)(c0 + c) * R + r0 + r] = f2bf(T[r][c]);
  }
}

// ---------------- QKV GEMM: bf16 MFMA, WHICH-specialized epilogue ----------------
template <int WHICH>
__global__ __launch_bounds__(256) void qkv_gemm_w(
    const unsigned short* __restrict__ A, const unsigned short* __restrict__ Bt,
    const float* __restrict__ bq, const float* __restrict__ tq,
    unsigned short* __restrict__ dst) {
  __shared__ unsigned short As[128 * 32];
  __shared__ unsigned short Bs[128 * 32];
  const int m0 = blockIdx.x * 128, n0 = blockIdx.y * 128;
  const int tid = threadIdx.x, l = tid & 63, w = tid >> 6;
  const int wm = w >> 1, wn = w & 1;
  const int grp = l >> 4, col = l & 15;
  f32x4 acc[4][4];
#pragma unroll
  for (int mi = 0; mi < 4; ++mi)
#pragma unroll
    for (int ni = 0; ni < 4; ++ni) acc[mi][ni] = (f32x4){0.f, 0.f, 0.f, 0.f};

  for (int k0 = 0; k0 < 1024; k0 += 32) {
    __syncthreads();
#pragma unroll
    for (int i = 0; i < 2; ++i) {
      int seg = i * 256 + w * 64 + l;
      int mr = seg >> 2, kq = seg & 3;
      gload_lds16(A + (size_t)(m0 + mr) * 1024 + k0 + kq * 8,
                  &As[(i * 256 + w * 64) * 8]);
      gload_lds16(Bt + (size_t)(n0 + mr) * 1024 + k0 + kq * 8,
                  &Bs[(i * 256 + w * 64) * 8]);
    }
    __syncthreads();
    short8 af[4], bfv[4];
#pragma unroll
    for (int mi = 0; mi < 4; ++mi)
      af[mi] = *(const short8*)&As[(wm * 64 + mi * 16 + col) * 32 + grp * 8];
#pragma unroll
    for (int ni = 0; ni < 4; ++ni)
      bfv[ni] = *(const short8*)&Bs[(wn * 64 + ni * 16 + col) * 32 + grp * 8];
#pragma unroll
    for (int mi = 0; mi < 4; ++mi)
#pragma unroll
      for (int ni = 0; ni < 4; ++ni)
        acc[mi][ni] = __builtin_amdgcn_mfma_f32_16x16x32_bf16(af[mi], bfv[ni], acc[mi][ni], 0, 0, 0);
  }

  const int bidx = m0 >> 10;
  float biasv[4];
  int hhv[4], dv[4];
#pragma unroll
  for (int ni = 0; ni < 4; ++ni) {
    int c2 = n0 + wn * 64 + ni * 16 + col;
    biasv[ni] = bq[c2] + tq[bidx * 3072 + c2];
    hhv[ni] = c2 >> 6;
    dv[ni] = c2 & 63;
  }
  if (WHICH == 2) {
    int t = (m0 & 1023) + wm * 64;
#pragma unroll
    for (int ni = 0; ni < 4; ++ni) {
      size_t rowb = ((size_t)(bidx * 16 + hhv[ni]) * 64 + dv[ni]) * 1024;
      int swz = (dv[ni] & 7) << 3;
#pragma unroll
      for (int rr = 0; rr < 4; ++rr) {
        int kbase = (grp * 4 + rr) * 4;
        int colix = t + ((kbase & ~7) ^ swz) + (kbase & 7);
        us4 pk;
#pragma unroll
        for (int mi = 0; mi < 4; ++mi) pk[mi] = f2bf(acc[mi][ni][rr] + biasv[ni]);
        *(us4*)&dst[rowb + colix] = pk;
      }
    }
  } else if (WHICH == 1) {
#pragma unroll
    for (int mi = 0; mi < 4; ++mi)
#pragma unroll
      for (int rr = 0; rr < 4; ++rr) {
        int nn = (m0 + wm * 64 + mi * 16 + grp * 4 + rr) & 1023;
#pragma unroll
        for (int ni = 0; ni < 4; ++ni) {
          size_t bhh = (size_t)(bidx * 16 + hhv[ni]);
          dst[(bhh * 1024 + nn) * 64 + (dv[ni] ^ ((nn & 7) << 3))] =
              f2bf(acc[mi][ni][rr] + biasv[ni]);
        }
      }
  } else {
#pragma unroll
    for (int mi = 0; mi < 4; ++mi)
#pragma unroll
      for (int rr = 0; rr < 4; ++rr) {
        int nn = (m0 + wm * 64 + mi * 16 + grp * 4 + rr) & 1023;
#pragma unroll
        for (int ni = 0; ni < 4; ++ni) {
          size_t bhh = (size_t)(bidx * 16 + hhv[ni]);
          dst[(bhh * 1024 + nn) * 64 + dv[ni]] = f2bf(acc[mi][ni][rr] + biasv[ni]);
        }
      }
  }
}

// ---------------- output projection: bf16 MFMA ----------------
__global__ __launch_bounds__(256) void out_gemm_mfma(
    const unsigned short* __restrict__ A, const unsigned short* __restrict__ Bt,
    const float* __restrict__ bias, float* __restrict__ out) {
  __shared__ unsigned short As[128 * 32];
  __shared__ unsigned short Bs[128 * 32];
  const int m0 = blockIdx.x * 128, n0 = blockIdx.y * 128;
  const int tid = threadIdx.x, l = tid & 63, w = tid >> 6;
  const int wm = w >> 1, wn = w & 1;
  const int grp = l >> 4, col = l & 15;
  f32x4 acc[4][4];
#pragma unroll
  for (int mi = 0; mi < 4; ++mi)
#pragma unroll
    for (int ni = 0; ni < 4; ++ni) acc[mi][ni] = (f32x4){0.f, 0.f, 0.f, 0.f};

  for (int k0 = 0; k0 < 1024; k0 += 32) {
    __syncthreads();
#pragma unroll
    for (int i = 0; i < 2; ++i) {
      int seg = i * 256 + w * 64 + l;
      int mr = seg >> 2, kq = seg & 3;
      gload_lds16(A + (size_t)(m0 + mr) * 1024 + k0 + kq * 8,
                  &As[(i * 256 + w * 64) * 8]);
      gload_lds16(Bt + (size_t)(n0 + mr) * 1024 + k0 + kq * 8,
                  &Bs[(i * 256 + w * 64) * 8]);
    }
    __syncthreads();
    short8 af[4], bfv[4];
#pragma unroll
    for (int mi = 0; mi < 4; ++mi)
      af[mi] = *(const short8*)&As[(wm * 64 + mi * 16 + col) * 32 + grp * 8];
#pragma unroll
    for (int ni = 0; ni < 4; ++ni)
      bfv[ni] = *(const short8*)&Bs[(wn * 64 + ni * 16 + col) * 32 + grp * 8];
#pragma unroll
    for (int mi = 0; mi < 4; ++mi)
#pragma unroll
      for (int ni = 0; ni < 4; ++ni)
        acc[mi][ni] = __builtin_amdgcn_mfma_f32_16x16x32_bf16(af[mi], bfv[ni], acc[mi][ni], 0, 0, 0);
  }
  float bv[4];
#pragma unroll
  for (int ni = 0; ni < 4; ++ni) bv[ni] = bias[n0 + wn * 64 + ni * 16 + col];
#pragma unroll
  for (int mi = 0; mi < 4; ++mi)
#pragma unroll
    for (int rr = 0; rr < 4; ++rr) {
      int row = m0 + wm * 64 + mi * 16 + grp * 4 + rr;
#pragma unroll
      for (int ni = 0; ni < 4; ++ni) {
        int c = n0 + wn * 64 + ni * 16 + col;
        out[(size_t)row * 1024 + c] = acc[mi][ni][rr] + bv[ni];
      }
    }
}

// ---------------- G' GEMM: G'[n*1025 + j] = q_n . Er'[j]; zero the skew hole ----------------
__global__ __launch_bounds__(256) void g_gemm2(
    const unsigned short* __restrict__ qb, int bh_base,
    const unsigned short* __restrict__ Er_bf,
    unsigned short* __restrict__ Gp) {
  const int n0 = blockIdx.x * 64;
  const int jq = blockIdx.y;       // 0..3
  const int bhl = blockIdx.z;
  const int bh = bh_base + bhl;
  const int tid = threadIdx.x, l = tid & 63, w = tid >> 6;
  const int grp = l >> 4, col = l & 15;
  const int jw = jq * 256 + w * 64;

  short8 aq[4][2];
#pragma unroll
  for (int rf = 0; rf < 4; ++rf)
#pragma unroll
    for (int dc = 0; dc < 2; ++dc)
      aq[rf][dc] = *(const short8*)(qb + ((size_t)bh * SEQ + n0 + rf * 16 + col) * HD + dc * 32 + grp * 8);

  f32x4 acc[4][4];
#pragma unroll
  for (int rf = 0; rf < 4; ++rf)
#pragma unroll
    for (int cf = 0; cf < 4; ++cf) acc[rf][cf] = (f32x4){0.f, 0.f, 0.f, 0.f};

#pragma unroll
  for (int cf = 0; cf < 4; ++cf)
#pragma unroll
    for (int dc = 0; dc < 2; ++dc) {
      short8 bfrag = *(const short8*)(Er_bf + (size_t)(jw + cf * 16 + col) * HD + dc * 32 + grp * 8);
#pragma unroll
      for (int rf = 0; rf < 4; ++rf)
        acc[rf][cf] = __builtin_amdgcn_mfma_f32_16x16x32_bf16(aq[rf][dc], bfrag, acc[rf][cf], 0, 0, 0);
    }

#pragma unroll
  for (int rf = 0; rf < 4; ++rf)
#pragma unroll
    for (int cf = 0; cf < 4; ++cf)
#pragma unroll
      for (int rr = 0; rr < 4; ++rr) {
        int n = n0 + rf * 16 + grp * 4 + rr;
        int j = jw + cf * 16 + col;
        Gp[((size_t)(bhl * SEQ + n)) * GROW + j] = f2bf(acc[rf][cf][rr]);
      }
  if (jq == 3 && tid < 64) {
    int n = n0 + tid;
    Gp[((size_t)(bhl * SEQ + n)) * GROW + 1024] = 0;
  }
}

// ---------------- flash attention: QBLK=128, P overlaid on Band, 2 barriers/step ----------------
// r14-proven structure. Barrier A between the last DS read of BandP and the async
// STAGE_BAND issue (global_load_lds's LDS write is unordered with the DS pipe —
// r12/13 corruption without the drain). Exact rescale. Grid = 8 tiles x slab_bh;
// slab=128 doubles resident blocks (grid was the occupancy limit at slab=64).
__global__ __launch_bounds__(256) void attn_kernel(
    const unsigned short* __restrict__ qb, const unsigned short* __restrict__ ksw,
    const unsigned short* __restrict__ vtsw, const unsigned short* __restrict__ Gp,
    unsigned short* __restrict__ attn_o, int bh_base) {
  __shared__ __align__(16) unsigned short KsL[2][4096];
  __shared__ __align__(16) unsigned short VtL[2][4096];
  __shared__ __align__(16) unsigned short BandP[128][72];  // Band ∪ P (wave-private rows)

  const int wg = blockIdx.x + 8 * blockIdx.y;
  const int chunk = gridDim.y;  // nwg/8
  const int nid = (wg & 7) * chunk + (wg >> 3);
  const int bhl = nid >> 3;
  const int n0 = (nid & 7) * 128;
  const int bh = bh_base + bhl;
  const int b = bh >> 4, h = bh & 15;
  const int tid = threadIdx.x, lane = tid & 63, wq = tid >> 6;
  const int grp = lane >> 4, col = lane & 15;

  short8 aq[2][2];
#pragma unroll
  for (int nf = 0; nf < 2; ++nf)
#pragma unroll
    for (int dc = 0; dc < 2; ++dc)
      aq[nf][dc] = *(const short8*)(qb + ((size_t)(bh * SEQ + n0 + wq * 32 + nf * 16 + col)) * HD + dc * 32 + grp * 8);

  f32x4 acco[2][4];
#pragma unroll
  for (int nf = 0; nf < 2; ++nf)
#pragma unroll
    for (int oc = 0; oc < 4; ++oc) acco[nf][oc] = (f32x4){0.f, 0.f, 0.f, 0.f};
  float mrun[2] = {-INFINITY, -INFINITY}, lrun[2] = {0.f, 0.f};

  const float scale2 = 0.125f * LOG2E;
  const unsigned short* kbh = ksw + (size_t)bh * SEQ * HD;
  const unsigned short* vbh = vtsw + (size_t)bh * HD * SEQ;
  const unsigned short* gbase = Gp + (size_t)(bhl * SEQ + n0) * GROW + (1016 - n0);

  auto STAGE_KV = [&](int buf, int m0) {
#pragma unroll
    for (int i = 0; i < 2; ++i) {
      int gi = i * 256 + wq * 64 + lane;
      int row = gi >> 3, gc = gi & 7;
      gload_lds16(kbh + (((size_t)(m0 + row)) << 6) + gc * 8,
                  &KsL[buf][(i * 256 + wq * 64) * 8]);
      gload_lds16(vbh + (((size_t)row) << 10) + m0 + gc * 8,
                  &VtL[buf][(i * 256 + wq * 64) * 8]);
    }
  };
  auto STAGE_BAND = [&](int m0) {  // wave wq stages its own rows [wq*32, +32)
    const unsigned short* gsrc = gbase + m0;
    unsigned short* bdst = &BandP[0][0];
    const int g0 = wq * 288;
#pragma unroll
    for (int it = 0; it < 4; ++it) {
      int g = g0 + it * 64 + lane;
      int r = g / 9, seg = g - r * 9;
      gload_lds16(gsrc + r * 1024 + seg * 8, bdst + g * 8);
    }
    if (lane < 32) {
      int g = g0 + 256 + lane;
      int r = g / 9, seg = g - r * 9;
      gload_lds16(gsrc + r * 1024 + seg * 8, bdst + g * 8);
    }
  };

  STAGE_KV(0, 0);
  STAGE_BAND(0);
  __syncthreads();

  for (int t = 0; t < 16; ++t) {
    const int cur = t & 1;
    if (t < 15) STAGE_KV(cur ^ 1, (t + 1) * 64);
    // QK^T swapped
    f32x4 acc[2][4];
#pragma unroll
    for (int nf = 0; nf < 2; ++nf)
#pragma unroll
      for (int mc = 0; mc < 4; ++mc) acc[nf][mc] = (f32x4){0.f, 0.f, 0.f, 0.f};
    __builtin_amdgcn_s_setprio(1);
#pragma unroll
    for (int mc = 0; mc < 4; ++mc)
#pragma unroll
      for (int dc = 0; dc < 2; ++dc) {
        short8 bk = *(const short8*)&KsL[cur][(mc * 16 + col) * 64 + (((dc * 4 + grp) ^ (col & 7)) << 3)];
#pragma unroll
        for (int nf = 0; nf < 2; ++nf)
          acc[nf][mc] = __builtin_amdgcn_mfma_f32_16x16x32_bf16(bk, aq[nf][dc], acc[nf][mc], 0, 0, 0);
      }
    __builtin_amdgcn_s_setprio(0);
    // lane-local online softmax (log2 domain, EXACT rescale); P overwrites Band row
#pragma unroll
    for (int nf = 0; nf < 2; ++nf) {
      const int dr = wq * 32 + nf * 16 + col;
      float s[4][4];
#pragma unroll
      for (int mc = 0; mc < 4; ++mc)
#pragma unroll
        for (int r = 0; r < 4; ++r)
          s[mc][r] = fmaf(acc[nf][mc][r], scale2, bf2f(BandP[dr][7 + mc * 16 + grp * 4 + r]));
      float mx = s[0][0];
#pragma unroll
      for (int mc = 0; mc < 4; ++mc)
#pragma unroll
        for (int r = 0; r < 4; ++r) mx = fmaxf(mx, s[mc][r]);
      mx = fmaxf(mx, __shfl_xor(mx, 16));
      mx = fmaxf(mx, __shfl_xor(mx, 32));
      if (mx > mrun[nf]) {  // exact: keep P <= 1 (bf16 precision budget)
        float cr = hexp2(mrun[nf] - mx);
        mrun[nf] = mx;
        lrun[nf] *= cr;
#pragma unroll
        for (int oc = 0; oc < 4; ++oc)
#pragma unroll
          for (int r = 0; r < 4; ++r) acco[nf][oc][r] *= cr;
      }
      float p[4][4];
#pragma unroll
      for (int mc = 0; mc < 4; ++mc)
#pragma unroll
        for (int r = 0; r < 4; ++r) {
          p[mc][r] = hexp2(s[mc][r] - mrun[nf]);
          lrun[nf] += p[mc][r];
        }
      unsigned int wpk[8];
#pragma unroll
      for (int r = 0; r < 4; ++r)
#pragma unroll
        for (int mh = 0; mh < 2; ++mh)
          asm("v_cvt_pk_bf16_f32 %0, %1, %2"
              : "=v"(wpk[r * 2 + mh]) : "v"(p[mh * 2][r]), "v"(p[mh * 2 + 1][r]));
      *(u32x4*)&BandP[dr][grp * 16] = (u32x4){wpk[0], wpk[1], wpk[2], wpk[3]};
      *(u32x4*)&BandP[dr][grp * 16 + 8] = (u32x4){wpk[4], wpk[5], wpk[6], wpk[7]};
    }
    // hoist ap fragments to regs (same-wave DS, safe without barrier)
    short8 ap[2][2];
#pragma unroll
    for (int nf = 0; nf < 2; ++nf)
#pragma unroll
      for (int kc = 0; kc < 2; ++kc)
        ap[nf][kc] = *(const short8*)&BandP[wq * 32 + nf * 16 + col][kc * 32 + grp * 8];
    __syncthreads();  // A: DS drain — all BandP reads done before async overwrite
    if (t < 15) STAGE_BAND((t + 1) * 64);  // latency hides under PV
    // PV swapped (sigma k-order on both operands)
    __builtin_amdgcn_s_setprio(1);
#pragma unroll
    for (int oc = 0; oc < 4; ++oc)
#pragma unroll
      for (int kc = 0; kc < 2; ++kc) {
        short8 bv = *(const short8*)&VtL[cur][(oc * 16 + col) * 64 + (((kc * 4 + grp) ^ (col & 7)) << 3)];
#pragma unroll
        for (int nf = 0; nf < 2; ++nf)
          acco[nf][oc] = __builtin_amdgcn_mfma_f32_16x16x32_bf16(bv, ap[nf][kc], acco[nf][oc], 0, 0, 0);
      }
    __builtin_amdgcn_s_setprio(0);
    __syncthreads();  // B: drains KV + Band prefetches; protects buf reuse
  }
  // epilogue
#pragma unroll
  for (int nf = 0; nf < 2; ++nf) {
    float tot = lrun[nf];
    tot += __shfl_xor(tot, 16);
    tot += __shfl_xor(tot, 32);
    float inv = 1.0f / tot;
    const int n = n0 + wq * 32 + nf * 16 + col;
#pragma unroll
    for (int oc = 0; oc < 4; ++oc) {
      us4 pk;
#pragma unroll
      for (int r = 0; r < 4; ++r) pk[r] = f2bf(acco[nf][oc][r] * inv);
      *(us4*)&attn_o[((size_t)(b * SEQ + n)) * CH + h * HD + oc * 16 + grp * 4] = pk;
    }
  }
}

extern "C" void kernel_launch(void* const* d_in, const int* in_sizes, int n_in,
                              void* d_out, int out_size, void* d_ws, size_t ws_size,
                              hipStream_t stream) {
  const float* x        = (const float*)d_in[0];
  const float* time_emb = (const float*)d_in[1];
  const float* W_qkv    = (const float*)d_in[2];
  const float* b_qkv    = (const float*)d_in[3];
  const float* W_time   = (const float*)d_in[4];
  const float* b_time   = (const float*)d_in[5];
  const float* W_out    = (const float*)d_in[6];
  const float* b_out    = (const float*)d_in[7];
  const float* Er       = (const float*)d_in[8];
  float* out = (float*)d_out;

  char* p = (char*)d_ws;
  float* tqkv = (float*)p;                      p += 98304;
  unsigned short* qb = (unsigned short*)p;      p += 16777216;
  unsigned short* ksw = (unsigned short*)p;     p += 16777216;
  unsigned short* vtsw = (unsigned short*)p;    p += 16777216;
  unsigned short* attn_o = (unsigned short*)p;  p += 16777216;
  unsigned short* Er_bf = (unsigned short*)p;   p += 131072;
  unsigned short* Wout_t = (unsigned short*)p;  p += 2097152;
  unsigned short* x_bf = (unsigned short*)p;               // 16 MB (prep, then dead)
  unsigned short* Wqkv_t = x_bf + (size_t)8388608;         // 6 MB (prep, then dead)
  unsigned short* Gp = (unsigned short*)p;                 // slab Gp, aliases prep region

  size_t fixed = (size_t)(p - (char*)d_ws);
  // cascade: slab=128 (single attn launch, 1024 blocks -> grid no longer the
  // occupancy limit) if Gp fits (268.7 MB); else 64 (r14-proven); else 32.
  const size_t GP_PER_BH = (size_t)SEQ * GROW * 2;  // 2,099,200 B
  int slab_bh = (ws_size >= fixed + 128 * GP_PER_BH) ? 128
              : (ws_size >= fixed + 64 * GP_PER_BH) ? 64 : 32;
  int nslab = 128 / slab_bh;

  er_convert_kernel<<<256, 256, 0, stream>>>(Er, Er_bf);
  time_proj_kernel<<<96, 256, 0, stream>>>(time_emb, W_time, b_time, tqkv);
  convert_bf_kernel<<<4096, 256, 0, stream>>>(x, x_bf, 1048576);
  transpose_bf_kernel<<<dim3(48, 16), 256, 0, stream>>>(W_qkv, Wqkv_t, 1024, 3072);
  transpose_bf_kernel<<<dim3(16, 16), 256, 0, stream>>>(W_out, Wout_t, 1024, 1024);
  qkv_gemm_w<0><<<dim3(64, 8), 256, 0, stream>>>(x_bf, Wqkv_t, b_qkv, tqkv, qb);
  qkv_gemm_w<1><<<dim3(64, 8), 256, 0, stream>>>(x_bf, Wqkv_t + (size_t)1048576,
                                                 b_qkv + 1024, tqkv + 1024, ksw);
  qkv_gemm_w<2><<<dim3(64, 8), 256, 0, stream>>>(x_bf, Wqkv_t + (size_t)2097152,
                                                 b_qkv + 2048, tqkv + 2048, vtsw);
  for (int s = 0; s < nslab; ++s) {
    int bh_base = s * slab_bh;
    g_gemm2<<<dim3(16, 4, slab_bh), 256, 0, stream>>>(qb, bh_base, Er_bf, Gp);
    attn_kernel<<<dim3(8, slab_bh), 256, 0, stream>>>(qb, ksw, vtsw, Gp, attn_o, bh_base);
  }
  out_gemm_mfma<<<dim3(64, 8), 256, 0, stream>>>(attn_o, Wout_t, b_out, out);
}

// Round 17
// 342.980 us; speedup vs baseline: 1.0788x; 1.0676x over previous
//
#include <hip/hip_runtime.h>
#include <math.h>

typedef __attribute__((ext_vector_type(8))) short short8;
typedef __attribute__((ext_vector_type(8))) unsigned short ushort8;
typedef __attribute__((ext_vector_type(4))) unsigned short us4;
typedef __attribute__((ext_vector_type(4))) unsigned int u32x4;
typedef __attribute__((ext_vector_type(4))) float f32x4;

#define NH 16
#define HD 64
#define SEQ 1024
#define NB 8
#define CH 1024
#define TD 256
#define GROW 1025          // flat row stride of G' (the skew trick; must be exactly 1025)
#define GSTRIDE 1049616    // per-bh byte stride: 1024*1025 + OFS(1) + tail pad, 16-mult
#define LOG2E 1.4426950408889634f

__device__ __forceinline__ unsigned short f2bf(float f) {
  union { float f; unsigned int u; } v; v.f = f;
  unsigned int r = v.u + 0x7FFFu + ((v.u >> 16) & 1u);
  return (unsigned short)(r >> 16);
}
__device__ __forceinline__ float bf2f(unsigned short s) {
  union { unsigned int u; float f; } v; v.u = ((unsigned int)s) << 16;
  return v.f;
}
__device__ __forceinline__ float hexp2(float x) {
  float r;
  asm("v_exp_f32 %0, %1" : "=v"(r) : "v"(x));
  return r;
}
__device__ __forceinline__ void gload_lds16(const void* g, void* l) {
  __builtin_amdgcn_global_load_lds(
      (const __attribute__((address_space(1))) unsigned int*)g,
      (__attribute__((address_space(3))) unsigned int*)l, 16, 0, 0);
}

// ---------------- time projection (fp32) ----------------
__global__ __launch_bounds__(256) void time_proj_kernel(
    const float* __restrict__ time_emb, const float* __restrict__ W_time,
    const float* __restrict__ b_time, float* __restrict__ tqkv) {
  int idx = blockIdx.x * 256 + threadIdx.x;
  if (idx >= NB * 3072) return;
  int b = idx / 3072, c = idx % 3072;
  float s = b_time[c];
  for (int t = 0; t < TD; ++t) s += time_emb[b * TD + t] * W_time[t * 3072 + c];
  tqkv[idx] = s;
}

// ---------------- Er fp32 -> bf16, scaled by log2e ----------------
__global__ __launch_bounds__(256) void er_convert_kernel(
    const float* __restrict__ Er, unsigned short* __restrict__ Er_bf) {
  int i = blockIdx.x * 256 + threadIdx.x;
  if (i < SEQ * HD) Er_bf[i] = f2bf(Er[i] * LOG2E);
}

// ---------------- fp32 -> bf16 vector convert ----------------
__global__ __launch_bounds__(256) void convert_bf_kernel(
    const float* __restrict__ in, unsigned short* __restrict__ out, int n8) {
  int i = blockIdx.x * 256 + threadIdx.x;
  if (i >= n8) return;
  float4 a = ((const float4*)in)[2 * i];
  float4 b = ((const float4*)in)[2 * i + 1];
  ushort8 o;
  o[0] = f2bf(a.x); o[1] = f2bf(a.y); o[2] = f2bf(a.z); o[3] = f2bf(a.w);
  o[4] = f2bf(b.x); o[5] = f2bf(b.y); o[6] = f2bf(b.z); o[7] = f2bf(b.w);
  ((ushort8*)out)[i] = o;
}

// ---------------- fp32 W[R][C] -> bf16 Wt[C][R] ----------------
__global__ __launch_bounds__(256) void transpose_bf_kernel(
    const float* __restrict__ W, unsigned short* __restrict__ Wt, int R, int Cc) {
  __shared__ float T[64][65];
  int r0 = blockIdx.y * 64, c0 = blockIdx.x * 64;
  for (int idx = threadIdx.x; idx < 4096; idx += 256) {
    int r = idx >> 6, c = idx & 63;
    T[r][c] = W[(size_t)(r0 + r) * Cc + c0 + c];
  }
  __syncthreads();
  for (int idx = threadIdx.x; idx < 4096; idx += 256) {
    int c = idx >> 6, r = idx & 63;
    Wt[(size_t)(c0 + c) * R + r0 + r] = f2bf(T[r][c]);
  }
}

// ---------------- QKV GEMM: bf16 MFMA, WHICH-specialized epilogue ----------------
template <int WHICH>
__global__ __launch_bounds__(256) void qkv_gemm_w(
    const unsigned short* __restrict__ A, const unsigned short* __restrict__ Bt,
    const float* __restrict__ bq, const float* __restrict__ tq,
    unsigned short* __restrict__ dst) {
  __shared__ unsigned short As[128 * 32];
  __shared__ unsigned short Bs[128 * 32];
  const int m0 = blockIdx.x * 128, n0 = blockIdx.y * 128;
  const int tid = threadIdx.x, l = tid & 63, w = tid >> 6;
  const int wm = w >> 1, wn = w & 1;
  const int grp = l >> 4, col = l & 15;
  f32x4 acc[4][4];
#pragma unroll
  for (int mi = 0; mi < 4; ++mi)
#pragma unroll
    for (int ni = 0; ni < 4; ++ni) acc[mi][ni] = (f32x4){0.f, 0.f, 0.f, 0.f};

  for (int k0 = 0; k0 < 1024; k0 += 32) {
    __syncthreads();
#pragma unroll
    for (int i = 0; i < 2; ++i) {
      int seg = i * 256 + w * 64 + l;
      int mr = seg >> 2, kq = seg & 3;
      gload_lds16(A + (size_t)(m0 + mr) * 1024 + k0 + kq * 8,
                  &As[(i * 256 + w * 64) * 8]);
      gload_lds16(Bt + (size_t)(n0 + mr) * 1024 + k0 + kq * 8,
                  &Bs[(i * 256 + w * 64) * 8]);
    }
    __syncthreads();
    short8 af[4], bfv[4];
#pragma unroll
    for (int mi = 0; mi < 4; ++mi)
      af[mi] = *(const short8*)&As[(wm * 64 + mi * 16 + col) * 32 + grp * 8];
#pragma unroll
    for (int ni = 0; ni < 4; ++ni)
      bfv[ni] = *(const short8*)&Bs[(wn * 64 + ni * 16 + col) * 32 + grp * 8];
#pragma unroll
    for (int mi = 0; mi < 4; ++mi)
#pragma unroll
      for (int ni = 0; ni < 4; ++ni)
        acc[mi][ni] = __builtin_amdgcn_mfma_f32_16x16x32_bf16(af[mi], bfv[ni], acc[mi][ni], 0, 0, 0);
  }

  const int bidx = m0 >> 10;
  float biasv[4];
  int hhv[4], dv[4];
#pragma unroll
  for (int ni = 0; ni < 4; ++ni) {
    int c2 = n0 + wn * 64 + ni * 16 + col;
    biasv[ni] = bq[c2] + tq[bidx * 3072 + c2];
    hhv[ni] = c2 >> 6;
    dv[ni] = c2 & 63;
  }
  if (WHICH == 2) {
    int t = (m0 & 1023) + wm * 64;
#pragma unroll
    for (int ni = 0; ni < 4; ++ni) {
      size_t rowb = ((size_t)(bidx * 16 + hhv[ni]) * 64 + dv[ni]) * 1024;
      int swz = (dv[ni] & 7) << 3;
#pragma unroll
      for (int rr = 0; rr < 4; ++rr) {
        int kbase = (grp * 4 + rr) * 4;
        int colix = t + ((kbase & ~7) ^ swz) + (kbase & 7);
        us4 pk;
#pragma unroll
        for (int mi = 0; mi < 4; ++mi) pk[mi] = f2bf(acc[mi][ni][rr] + biasv[ni]);
        *(us4*)&dst[rowb + colix] = pk;
      }
    }
  } else if (WHICH == 1) {
#pragma unroll
    for (int mi = 0; mi < 4; ++mi)
#pragma unroll
      for (int rr = 0; rr < 4; ++rr) {
        int nn = (m0 + wm * 64 + mi * 16 + grp * 4 + rr) & 1023;
#pragma unroll
        for (int ni = 0; ni < 4; ++ni) {
          size_t bhh = (size_t)(bidx * 16 + hhv[ni]);
          dst[(bhh * 1024 + nn) * 64 + (dv[ni] ^ ((nn & 7) << 3))] =
              f2bf(acc[mi][ni][rr] + biasv[ni]);
        }
      }
  } else {
#pragma unroll
    for (int mi = 0; mi < 4; ++mi)
#pragma unroll
      for (int rr = 0; rr < 4; ++rr) {
        int nn = (m0 + wm * 64 + mi * 16 + grp * 4 + rr) & 1023;
#pragma unroll
        for (int ni = 0; ni < 4; ++ni) {
          size_t bhh = (size_t)(bidx * 16 + hhv[ni]);
          dst[(bhh * 1024 + nn) * 64 + dv[ni]] = f2bf(acc[mi][ni][rr] + biasv[ni]);
        }
      }
  }
}

// ---------------- output projection: bf16 MFMA ----------------
__global__ __launch_bounds__(256) void out_gemm_mfma(
    const unsigned short* __restrict__ A, const unsigned short* __restrict__ Bt,
    const float* __restrict__ bias, float* __restrict__ out) {
  __shared__ unsigned short As[128 * 32];
  __shared__ unsigned short Bs[128 * 32];
  const int m0 = blockIdx.x * 128, n0 = blockIdx.y * 128;
  const int tid = threadIdx.x, l = tid & 63, w = tid >> 6;
  const int wm = w >> 1, wn = w & 1;
  const int grp = l >> 4, col = l & 15;
  f32x4 acc[4][4];
#pragma unroll
  for (int mi = 0; mi < 4; ++mi)
#pragma unroll
    for (int ni = 0; ni < 4; ++ni) acc[mi][ni] = (f32x4){0.f, 0.f, 0.f, 0.f};

  for (int k0 = 0; k0 < 1024; k0 += 32) {
    __syncthreads();
#pragma unroll
    for (int i = 0; i < 2; ++i) {
      int seg = i * 256 + w * 64 + l;
      int mr = seg >> 2, kq = seg & 3;
      gload_lds16(A + (size_t)(m0 + mr) * 1024 + k0 + kq * 8,
                  &As[(i * 256 + w * 64) * 8]);
      gload_lds16(Bt + (size_t)(n0 + mr) * 1024 + k0 + kq * 8,
                  &Bs[(i * 256 + w * 64) * 8]);
    }
    __syncthreads();
    short8 af[4], bfv[4];
#pragma unroll
    for (int mi = 0; mi < 4; ++mi)
      af[mi] = *(const short8*)&As[(wm * 64 + mi * 16 + col) * 32 + grp * 8];
#pragma unroll
    for (int ni = 0; ni < 4; ++ni)
      bfv[ni] = *(const short8*)&Bs[(wn * 64 + ni * 16 + col) * 32 + grp * 8];
#pragma unroll
    for (int mi = 0; mi < 4; ++mi)
#pragma unroll
      for (int ni = 0; ni < 4; ++ni)
        acc[mi][ni] = __builtin_amdgcn_mfma_f32_16x16x32_bf16(af[mi], bfv[ni], acc[mi][ni], 0, 0, 0);
  }
  float bv[4];
#pragma unroll
  for (int ni = 0; ni < 4; ++ni) bv[ni] = bias[n0 + wn * 64 + ni * 16 + col];
#pragma unroll
  for (int mi = 0; mi < 4; ++mi)
#pragma unroll
    for (int rr = 0; rr < 4; ++rr) {
      int row = m0 + wm * 64 + mi * 16 + grp * 4 + rr;
#pragma unroll
      for (int ni = 0; ni < 4; ++ni) {
        int c = n0 + wn * 64 + ni * 16 + col;
        out[(size_t)row * 1024 + c] = acc[mi][ni][rr] + bv[ni];
      }
    }
}

// ---------------- G' GEMM -> int8 (biased ubyte, scale 1/64), +1 byte offset ----------------
// Gp8[bh*GSTRIDE + n*1025 + j + 1] = round(G'[n][j]*64)+128; skew hole (j=1024) = 128 (0.0).
// +1 offset makes every attn band window start 16B-aligned (1024 == 0 mod 16).
__global__ __launch_bounds__(256) void g_gemm8(
    const unsigned short* __restrict__ qb,
    const unsigned short* __restrict__ Er_bf,
    unsigned char* __restrict__ Gp8) {
  const int n0 = blockIdx.x * 64;
  const int jq = blockIdx.y;       // 0..3
  const int bhl = blockIdx.z;
  const int tid = threadIdx.x, l = tid & 63, w = tid >> 6;
  const int grp = l >> 4, col = l & 15;
  const int jw = jq * 256 + w * 64;
  unsigned char* gbh = Gp8 + (size_t)bhl * GSTRIDE;

  short8 aq[4][2];
#pragma unroll
  for (int rf = 0; rf < 4; ++rf)
#pragma unroll
    for (int dc = 0; dc < 2; ++dc)
      aq[rf][dc] = *(const short8*)(qb + ((size_t)bhl * SEQ + n0 + rf * 16 + col) * HD + dc * 32 + grp * 8);

  f32x4 acc[4][4];
#pragma unroll
  for (int rf = 0; rf < 4; ++rf)
#pragma unroll
    for (int cf = 0; cf < 4; ++cf) acc[rf][cf] = (f32x4){0.f, 0.f, 0.f, 0.f};

#pragma unroll
  for (int cf = 0; cf < 4; ++cf)
#pragma unroll
    for (int dc = 0; dc < 2; ++dc) {
      short8 bfrag = *(const short8*)(Er_bf + (size_t)(jw + cf * 16 + col) * HD + dc * 32 + grp * 8);
#pragma unroll
      for (int rf = 0; rf < 4; ++rf)
        acc[rf][cf] = __builtin_amdgcn_mfma_f32_16x16x32_bf16(aq[rf][dc], bfrag, acc[rf][cf], 0, 0, 0);
    }

#pragma unroll
  for (int rf = 0; rf < 4; ++rf)
#pragma unroll
    for (int cf = 0; cf < 4; ++cf)
#pragma unroll
      for (int rr = 0; rr < 4; ++rr) {
        int n = n0 + rf * 16 + grp * 4 + rr;
        int j = jw + cf * 16 + col;
        float t = acc[rf][cf][rr] * 64.0f;
        t = fminf(fmaxf(t, -120.0f), 120.0f);
        int vi = (int)rintf(t);
        gbh[(size_t)n * GROW + j + 1] = (unsigned char)(vi + 128);
      }
  if (jq == 3 && tid < 64) {
    int n = n0 + tid;
    gbh[(size_t)n * GROW + 1025] = 128;  // skew hole -> 0.0
  }
}

// ---------------- flash attention: QBLK=128, int8 band, P overlaid, 48 KB LDS ----------------
// Band rows: 80 staged bytes (5 of 8 granule-slots) at row stride 128 B so the
// global_load_lds dest stays linear (base + slot*16) AND P (64 bf16 = 128 B) overlays
// the same rows (r14-proven same-lane-ordering). Barrier A between last BandP DS read
// and the async STAGE_BAND (r12/13 lesson). Exact rescale. Grid 8 x 128 = 1024 blocks,
// LDS 48 KB -> 3 blocks/CU (grid was the occupancy limiter at 512).
__global__ __launch_bounds__(256) void attn_kernel(
    const unsigned short* __restrict__ qb, const unsigned short* __restrict__ ksw,
    const unsigned short* __restrict__ vtsw, const unsigned char* __restrict__ Gp8,
    unsigned short* __restrict__ attn_o) {
  __shared__ __align__(16) unsigned short KsL[2][4096];
  __shared__ __align__(16) unsigned short VtL[2][4096];
  __shared__ __align__(16) unsigned char BandP[128][128];  // band bytes [0,80) ∪ P bf16 [0,128)

  const int wg = blockIdx.x + 8 * blockIdx.y;
  const int chunk = gridDim.y;  // 128
  const int nid = (wg & 7) * chunk + (wg >> 3);
  const int bhl = nid >> 3;
  const int n0 = (nid & 7) * 128;
  const int b = bhl >> 4, h = bhl & 15;
  const int tid = threadIdx.x, lane = tid & 63, wq = tid >> 6;
  const int grp = lane >> 4, col = lane & 15;

  short8 aq[2][2];
#pragma unroll
  for (int nf = 0; nf < 2; ++nf)
#pragma unroll
    for (int dc = 0; dc < 2; ++dc)
      aq[nf][dc] = *(const short8*)(qb + ((size_t)(bhl * SEQ + n0 + wq * 32 + nf * 16 + col)) * HD + dc * 32 + grp * 8);

  f32x4 acco[2][4];
#pragma unroll
  for (int nf = 0; nf < 2; ++nf)
#pragma unroll
    for (int oc = 0; oc < 4; ++oc) acco[nf][oc] = (f32x4){0.f, 0.f, 0.f, 0.f};
  float mrun[2] = {-INFINITY, -INFINITY}, lrun[2] = {0.f, 0.f};

  const float scale2 = 0.125f * LOG2E;
  const unsigned short* kbh = ksw + (size_t)bhl * SEQ * HD;
  const unsigned short* vbh = vtsw + (size_t)bhl * HD * SEQ;
  // band window start for row r at tile m0: Gp8 + bhl*GSTRIDE + (n0+r)*1024 + 1024 + m0
  const unsigned char* gb0 = Gp8 + (size_t)bhl * GSTRIDE + ((size_t)n0 + 1) * 1024;

  auto STAGE_KV = [&](int buf, int m0) {
#pragma unroll
    for (int i = 0; i < 2; ++i) {
      int gi = i * 256 + wq * 64 + lane;
      int row = gi >> 3, gc = gi & 7;
      gload_lds16(kbh + (((size_t)(m0 + row)) << 6) + gc * 8,
                  &KsL[buf][(i * 256 + wq * 64) * 8]);
      gload_lds16(vbh + (((size_t)row) << 10) + m0 + gc * 8,
                  &VtL[buf][(i * 256 + wq * 64) * 8]);
    }
  };
  auto STAGE_BAND = [&](int m0) {  // 1024 slots (8/row), issue only seg<5; dest linear
    const unsigned char* gsrc = gb0 + m0;
    unsigned char* bdst = &BandP[0][0];
    const int g0 = wq * 256;  // wave wq owns rows [wq*32, +32)
#pragma unroll
    for (int it = 0; it < 4; ++it) {
      int g = g0 + it * 64 + lane;
      if ((g & 7) < 5) {
        int r = g >> 3, seg = g & 7;
        gload_lds16(gsrc + (size_t)r * 1024 + seg * 16, bdst + g * 16);
      }
    }
  };

  STAGE_KV(0, 0);
  STAGE_BAND(0);
  __syncthreads();

  for (int t = 0; t < 16; ++t) {
    const int cur = t & 1;
    if (t < 15) STAGE_KV(cur ^ 1, (t + 1) * 64);
    // QK^T swapped
    f32x4 acc[2][4];
#pragma unroll
    for (int nf = 0; nf < 2; ++nf)
#pragma unroll
      for (int mc = 0; mc < 4; ++mc) acc[nf][mc] = (f32x4){0.f, 0.f, 0.f, 0.f};
    __builtin_amdgcn_s_setprio(1);
#pragma unroll
    for (int mc = 0; mc < 4; ++mc)
#pragma unroll
      for (int dc = 0; dc < 2; ++dc) {
        short8 bk = *(const short8*)&KsL[cur][(mc * 16 + col) * 64 + (((dc * 4 + grp) ^ (col & 7)) << 3)];
#pragma unroll
        for (int nf = 0; nf < 2; ++nf)
          acc[nf][mc] = __builtin_amdgcn_mfma_f32_16x16x32_bf16(bk, aq[nf][dc], acc[nf][mc], 0, 0, 0);
      }
    __builtin_amdgcn_s_setprio(0);
    // lane-local online softmax (log2 domain, EXACT rescale); int8 band decode
#pragma unroll
    for (int nf = 0; nf < 2; ++nf) {
      const int dr = wq * 32 + nf * 16 + col;
      float s[4][4];
#pragma unroll
      for (int mc = 0; mc < 4; ++mc) {
        unsigned wrd = *(const unsigned*)&BandP[dr][mc * 16 + grp * 4];
#pragma unroll
        for (int r = 0; r < 4; ++r) {
          float ubf = (float)((wrd >> (8 * r)) & 0xffu);   // -> v_cvt_f32_ubyteN
          s[mc][r] = fmaf(ubf, 0.015625f, fmaf(acc[nf][mc][r], scale2, -2.0f));
        }
      }
      float mx = s[0][0];
#pragma unroll
      for (int mc = 0; mc < 4; ++mc)
#pragma unroll
        for (int r = 0; r < 4; ++r) mx = fmaxf(mx, s[mc][r]);
      mx = fmaxf(mx, __shfl_xor(mx, 16));
      mx = fmaxf(mx, __shfl_xor(mx, 32));
      if (mx > mrun[nf]) {  // exact: keep P <= 1 (bf16 precision budget)
        float cr = hexp2(mrun[nf] - mx);
        mrun[nf] = mx;
        lrun[nf] *= cr;
#pragma unroll
        for (int oc = 0; oc < 4; ++oc)
#pragma unroll
          for (int r = 0; r < 4; ++r) acco[nf][oc][r] *= cr;
      }
      float p[4][4];
#pragma unroll
      for (int mc = 0; mc < 4; ++mc)
#pragma unroll
        for (int r = 0; r < 4; ++r) {
          p[mc][r] = hexp2(s[mc][r] - mrun[nf]);
          lrun[nf] += p[mc][r];
        }
      unsigned int wpk[8];
#pragma unroll
      for (int r = 0; r < 4; ++r)
#pragma unroll
        for (int mh = 0; mh < 2; ++mh)
          asm("v_cvt_pk_bf16_f32 %0, %1, %2"
              : "=v"(wpk[r * 2 + mh]) : "v"(p[mh * 2][r]), "v"(p[mh * 2 + 1][r]));
      *(u32x4*)&BandP[dr][grp * 32] = (u32x4){wpk[0], wpk[1], wpk[2], wpk[3]};
      *(u32x4*)&BandP[dr][grp * 32 + 16] = (u32x4){wpk[4], wpk[5], wpk[6], wpk[7]};
    }
    // hoist ap fragments to regs (same-wave DS, safe without barrier)
    short8 ap[2][2];
#pragma unroll
    for (int nf = 0; nf < 2; ++nf)
#pragma unroll
      for (int kc = 0; kc < 2; ++kc)
        ap[nf][kc] = *(const short8*)&BandP[wq * 32 + nf * 16 + col][kc * 64 + grp * 16];
    __syncthreads();  // A: DS drain — all BandP reads done before async overwrite
    if (t < 15) STAGE_BAND((t + 1) * 64);  // latency hides under PV
    // PV swapped (sigma k-order on both operands)
    __builtin_amdgcn_s_setprio(1);
#pragma unroll
    for (int oc = 0; oc < 4; ++oc)
#pragma unroll
      for (int kc = 0; kc < 2; ++kc) {
        short8 bv = *(const short8*)&VtL[cur][(oc * 16 + col) * 64 + (((kc * 4 + grp) ^ (col & 7)) << 3)];
#pragma unroll
        for (int nf = 0; nf < 2; ++nf)
          acco[nf][oc] = __builtin_amdgcn_mfma_f32_16x16x32_bf16(bv, ap[nf][kc], acco[nf][oc], 0, 0, 0);
      }
    __builtin_amdgcn_s_setprio(0);
    __syncthreads();  // B: drains KV + Band prefetches; protects buf reuse
  }
  // epilogue
#pragma unroll
  for (int nf = 0; nf < 2; ++nf) {
    float tot = lrun[nf];
    tot += __shfl_xor(tot, 16);
    tot += __shfl_xor(tot, 32);
    float inv = 1.0f / tot;
    const int n = n0 + wq * 32 + nf * 16 + col;
#pragma unroll
    for (int oc = 0; oc < 4; ++oc) {
      us4 pk;
#pragma unroll
      for (int r = 0; r < 4; ++r) pk[r] = f2bf(acco[nf][oc][r] * inv);
      *(us4*)&attn_o[((size_t)(b * SEQ + n)) * CH + h * HD + oc * 16 + grp * 4] = pk;
    }
  }
}

extern "C" void kernel_launch(void* const* d_in, const int* in_sizes, int n_in,
                              void* d_out, int out_size, void* d_ws, size_t ws_size,
                              hipStream_t stream) {
  const float* x        = (const float*)d_in[0];
  const float* time_emb = (const float*)d_in[1];
  const float* W_qkv    = (const float*)d_in[2];
  const float* b_qkv    = (const float*)d_in[3];
  const float* W_time   = (const float*)d_in[4];
  const float* b_time   = (const float*)d_in[5];
  const float* W_out    = (const float*)d_in[6];
  const float* b_out    = (const float*)d_in[7];
  const float* Er       = (const float*)d_in[8];
  float* out = (float*)d_out;

  char* p = (char*)d_ws;
  float* tqkv = (float*)p;                      p += 98304;
  unsigned short* qb = (unsigned short*)p;      p += 16777216;
  unsigned short* ksw = (unsigned short*)p;     p += 16777216;
  unsigned short* vtsw = (unsigned short*)p;    p += 16777216;
  unsigned short* attn_o = (unsigned short*)p;  p += 16777216;
  unsigned short* Er_bf = (unsigned short*)p;   p += 131072;
  unsigned short* Wout_t = (unsigned short*)p;  p += 2097152;
  unsigned short* x_bf = (unsigned short*)p;               // 16 MB (prep, then dead)
  unsigned short* Wqkv_t = x_bf + (size_t)8388608;         // 6 MB (prep, then dead)
  unsigned char* Gp8 = (unsigned char*)p;                  // 128 x GSTRIDE = 134.35 MB
                                                           // (fits the r14-proven budget)

  er_convert_kernel<<<256, 256, 0, stream>>>(Er, Er_bf);
  time_proj_kernel<<<96, 256, 0, stream>>>(time_emb, W_time, b_time, tqkv);
  convert_bf_kernel<<<4096, 256, 0, stream>>>(x, x_bf, 1048576);
  transpose_bf_kernel<<<dim3(48, 16), 256, 0, stream>>>(W_qkv, Wqkv_t, 1024, 3072);
  transpose_bf_kernel<<<dim3(16, 16), 256, 0, stream>>>(W_out, Wout_t, 1024, 1024);
  qkv_gemm_w<0><<<dim3(64, 8), 256, 0, stream>>>(x_bf, Wqkv_t, b_qkv, tqkv, qb);
  qkv_gemm_w<1><<<dim3(64, 8), 256, 0, stream>>>(x_bf, Wqkv_t + (size_t)1048576,
                                                 b_qkv + 1024, tqkv + 1024, ksw);
  qkv_gemm_w<2><<<dim3(64, 8), 256, 0, stream>>>(x_bf, Wqkv_t + (size_t)2097152,
                                                 b_qkv + 2048, tqkv + 2048, vtsw);
  g_gemm8<<<dim3(16, 4, 128), 256, 0, stream>>>(qb, Er_bf, Gp8);
  attn_kernel<<<dim3(8, 128), 256, 0, stream>>>(qb, ksw, vtsw, Gp8, attn_o);
  out_gemm_mfma<<<dim3(64, 8), 256, 0, stream>>>(attn_o, Wout_t, b_out, out);
}

// Round 19
// 318.555 us; speedup vs baseline: 1.1615x; 1.0767x over previous
//
#include <hip/hip_runtime.h>
#include <math.h>

typedef __attribute__((ext_vector_type(8))) short short8;
typedef __attribute__((ext_vector_type(8))) unsigned short ushort8;
typedef __attribute__((ext_vector_type(4))) unsigned short us4;
typedef __attribute__((ext_vector_type(4))) unsigned int u32x4;
typedef __attribute__((ext_vector_type(4))) float f32x4;

#define NH 16
#define HD 64
#define SEQ 1024
#define NB 8
#define CH 1024
#define TD 256
#define GROW 1025          // flat row stride of G' (the skew trick; must be exactly 1025)
#define GSTRIDE 1049616    // per-bh byte stride: 1024*1025 + OFS(1) + tail pad, 16-mult
#define LOG2E 1.4426950408889634f

__device__ __forceinline__ unsigned short f2bf(float f) {
  union { float f; unsigned int u; } v; v.f = f;
  unsigned int r = v.u + 0x7FFFu + ((v.u >> 16) & 1u);
  return (unsigned short)(r >> 16);
}
__device__ __forceinline__ float bf2f(unsigned short s) {
  union { unsigned int u; float f; } v; v.u = ((unsigned int)s) << 16;
  return v.f;
}
__device__ __forceinline__ float hexp2(float x) {
  float r;
  asm("v_exp_f32 %0, %1" : "=v"(r) : "v"(x));
  return r;
}
__device__ __forceinline__ void gload_lds16(const void* g, void* l) {
  __builtin_amdgcn_global_load_lds(
      (const __attribute__((address_space(1))) unsigned int*)g,
      (__attribute__((address_space(3))) unsigned int*)l, 16, 0, 0);
}

// ---------------- time projection (fp32) ----------------
__global__ __launch_bounds__(256) void time_proj_kernel(
    const float* __restrict__ time_emb, const float* __restrict__ W_time,
    const float* __restrict__ b_time, float* __restrict__ tqkv) {
  int idx = blockIdx.x * 256 + threadIdx.x;
  if (idx >= NB * 3072) return;
  int b = idx / 3072, c = idx % 3072;
  float s = b_time[c];
  for (int t = 0; t < TD; ++t) s += time_emb[b * TD + t] * W_time[t * 3072 + c];
  tqkv[idx] = s;
}

// ---------------- Er fp32 -> bf16, scaled by log2e ----------------
__global__ __launch_bounds__(256) void er_convert_kernel(
    const float* __restrict__ Er, unsigned short* __restrict__ Er_bf) {
  int i = blockIdx.x * 256 + threadIdx.x;
  if (i < SEQ * HD) Er_bf[i] = f2bf(Er[i] * LOG2E);
}

// ---------------- fp32 -> bf16 vector convert ----------------
__global__ __launch_bounds__(256) void convert_bf_kernel(
    const float* __restrict__ in, unsigned short* __restrict__ out, int n8) {
  int i = blockIdx.x * 256 + threadIdx.x;
  if (i >= n8) return;
  float4 a = ((const float4*)in)[2 * i];
  float4 b = ((const float4*)in)[2 * i + 1];
  ushort8 o;
  o[0] = f2bf(a.x); o[1] = f2bf(a.y); o[2] = f2bf(a.z); o[3] = f2bf(a.w);
  o[4] = f2bf(b.x); o[5] = f2bf(b.y); o[6] = f2bf(b.z); o[7] = f2bf(b.w);
  ((ushort8*)out)[i] = o;
}

// ---------------- fp32 W[R][C] -> bf16 Wt[C][R] ----------------
__global__ __launch_bounds__(256) void transpose_bf_kernel(
    const float* __restrict__ W, unsigned short* __restrict__ Wt, int R, int Cc) {
  __shared__ float T[64][65];
  int r0 = blockIdx.y * 64, c0 = blockIdx.x * 64;
  for (int idx = threadIdx.x; idx < 4096; idx += 256) {
    int r = idx >> 6, c = idx & 63;
    T[r][c] = W[(size_t)(r0 + r) * Cc + c0 + c];
  }
  __syncthreads();
  for (int idx = threadIdx.x; idx < 4096; idx += 256) {
    int c = idx >> 6, r = idx & 63;
    Wt[(size_t)(c0 + c) * R + r0 + r] = f2bf(T[r][c]);
  }
}

// ---------------- QKV GEMM: bf16 MFMA, WHICH-specialized epilogue ----------------
template <int WHICH>
__global__ __launch_bounds__(256) void qkv_gemm_w(
    const unsigned short* __restrict__ A, const unsigned short* __restrict__ Bt,
    const float* __restrict__ bq, const float* __restrict__ tq,
    unsigned short* __restrict__ dst) {
  __shared__ unsigned short As[128 * 32];
  __shared__ unsigned short Bs[128 * 32];
  const int m0 = blockIdx.x * 128, n0 = blockIdx.y * 128;
  const int tid = threadIdx.x, l = tid & 63, w = tid >> 6;
  const int wm = w >> 1, wn = w & 1;
  const int grp = l >> 4, col = l & 15;
  f32x4 acc[4][4];
#pragma unroll
  for (int mi = 0; mi < 4; ++mi)
#pragma unroll
    for (int ni = 0; ni < 4; ++ni) acc[mi][ni] = (f32x4){0.f, 0.f, 0.f, 0.f};

  for (int k0 = 0; k0 < 1024; k0 += 32) {
    __syncthreads();
#pragma unroll
    for (int i = 0; i < 2; ++i) {
      int seg = i * 256 + w * 64 + l;
      int mr = seg >> 2, kq = seg & 3;
      gload_lds16(A + (size_t)(m0 + mr) * 1024 + k0 + kq * 8,
                  &As[(i * 256 + w * 64) * 8]);
      gload_lds16(Bt + (size_t)(n0 + mr) * 1024 + k0 + kq * 8,
                  &Bs[(i * 256 + w * 64) * 8]);
    }
    __syncthreads();
    short8 af[4], bfv[4];
#pragma unroll
    for (int mi = 0; mi < 4; ++mi)
      af[mi] = *(const short8*)&As[(wm * 64 + mi * 16 + col) * 32 + grp * 8];
#pragma unroll
    for (int ni = 0; ni < 4; ++ni)
      bfv[ni] = *(const short8*)&Bs[(wn * 64 + ni * 16 + col) * 32 + grp * 8];
#pragma unroll
    for (int mi = 0; mi < 4; ++mi)
#pragma unroll
      for (int ni = 0; ni < 4; ++ni)
        acc[mi][ni] = __builtin_amdgcn_mfma_f32_16x16x32_bf16(af[mi], bfv[ni], acc[mi][ni], 0, 0, 0);
  }

  const int bidx = m0 >> 10;
  float biasv[4];
  int hhv[4], dv[4];
#pragma unroll
  for (int ni = 0; ni < 4; ++ni) {
    int c2 = n0 + wn * 64 + ni * 16 + col;
    biasv[ni] = bq[c2] + tq[bidx * 3072 + c2];
    hhv[ni] = c2 >> 6;
    dv[ni] = c2 & 63;
  }
  if (WHICH == 2) {
    int t = (m0 & 1023) + wm * 64;
#pragma unroll
    for (int ni = 0; ni < 4; ++ni) {
      size_t rowb = ((size_t)(bidx * 16 + hhv[ni]) * 64 + dv[ni]) * 1024;
      int swz = (dv[ni] & 7) << 3;
#pragma unroll
      for (int rr = 0; rr < 4; ++rr) {
        int kbase = (grp * 4 + rr) * 4;
        int colix = t + ((kbase & ~7) ^ swz) + (kbase & 7);
        us4 pk;
#pragma unroll
        for (int mi = 0; mi < 4; ++mi) pk[mi] = f2bf(acc[mi][ni][rr] + biasv[ni]);
        *(us4*)&dst[rowb + colix] = pk;
      }
    }
  } else if (WHICH == 1) {
#pragma unroll
    for (int mi = 0; mi < 4; ++mi)
#pragma unroll
      for (int rr = 0; rr < 4; ++rr) {
        int nn = (m0 + wm * 64 + mi * 16 + grp * 4 + rr) & 1023;
#pragma unroll
        for (int ni = 0; ni < 4; ++ni) {
          size_t bhh = (size_t)(bidx * 16 + hhv[ni]);
          dst[(bhh * 1024 + nn) * 64 + (dv[ni] ^ ((nn & 7) << 3))] =
              f2bf(acc[mi][ni][rr] + biasv[ni]);
        }
      }
  } else {
#pragma unroll
    for (int mi = 0; mi < 4; ++mi)
#pragma unroll
      for (int rr = 0; rr < 4; ++rr) {
        int nn = (m0 + wm * 64 + mi * 16 + grp * 4 + rr) & 1023;
#pragma unroll
        for (int ni = 0; ni < 4; ++ni) {
          size_t bhh = (size_t)(bidx * 16 + hhv[ni]);
          dst[(bhh * 1024 + nn) * 64 + dv[ni]] = f2bf(acc[mi][ni][rr] + biasv[ni]);
        }
      }
  }
}

// ---------------- output projection: bf16 MFMA ----------------
__global__ __launch_bounds__(256) void out_gemm_mfma(
    const unsigned short* __restrict__ A, const unsigned short* __restrict__ Bt,
    const float* __restrict__ bias, float* __restrict__ out) {
  __shared__ unsigned short As[128 * 32];
  __shared__ unsigned short Bs[128 * 32];
  const int m0 = blockIdx.x * 128, n0 = blockIdx.y * 128;
  const int tid = threadIdx.x, l = tid & 63, w = tid >> 6;
  const int wm = w >> 1, wn = w & 1;
  const int grp = l >> 4, col = l & 15;
  f32x4 acc[4][4];
#pragma unroll
  for (int mi = 0; mi < 4; ++mi)
#pragma unroll
    for (int ni = 0; ni < 4; ++ni) acc[mi][ni] = (f32x4){0.f, 0.f, 0.f, 0.f};

  for (int k0 = 0; k0 < 1024; k0 += 32) {
    __syncthreads();
#pragma unroll
    for (int i = 0; i < 2; ++i) {
      int seg = i * 256 + w * 64 + l;
      int mr = seg >> 2, kq = seg & 3;
      gload_lds16(A + (size_t)(m0 + mr) * 1024 + k0 + kq * 8,
                  &As[(i * 256 + w * 64) * 8]);
      gload_lds16(Bt + (size_t)(n0 + mr) * 1024 + k0 + kq * 8,
                  &Bs[(i * 256 + w * 64) * 8]);
    }
    __syncthreads();
    short8 af[4], bfv[4];
#pragma unroll
    for (int mi = 0; mi < 4; ++mi)
      af[mi] = *(const short8*)&As[(wm * 64 + mi * 16 + col) * 32 + grp * 8];
#pragma unroll
    for (int ni = 0; ni < 4; ++ni)
      bfv[ni] = *(const short8*)&Bs[(wn * 64 + ni * 16 + col) * 32 + grp * 8];
#pragma unroll
    for (int mi = 0; mi < 4; ++mi)
#pragma unroll
      for (int ni = 0; ni < 4; ++ni)
        acc[mi][ni] = __builtin_amdgcn_mfma_f32_16x16x32_bf16(af[mi], bfv[ni], acc[mi][ni], 0, 0, 0);
  }
  float bv[4];
#pragma unroll
  for (int ni = 0; ni < 4; ++ni) bv[ni] = bias[n0 + wn * 64 + ni * 16 + col];
#pragma unroll
  for (int mi = 0; mi < 4; ++mi)
#pragma unroll
    for (int rr = 0; rr < 4; ++rr) {
      int row = m0 + wm * 64 + mi * 16 + grp * 4 + rr;
#pragma unroll
      for (int ni = 0; ni < 4; ++ni) {
        int c = n0 + wn * 64 + ni * 16 + col;
        out[(size_t)row * 1024 + c] = acc[mi][ni][rr] + bv[ni];
      }
    }
}

// ---------------- G' GEMM -> int8 (biased ubyte, scale 1/64), +1 byte offset ----------------
// Gp8[bh*GSTRIDE + n*1025 + j + 1] = round(G'[n][j]*64)+128; skew hole (j=1024) = 128 (0.0).
// +1 offset makes every attn band window start 16B-aligned (1024 == 0 mod 16).
__global__ __launch_bounds__(256) void g_gemm8(
    const unsigned short* __restrict__ qb,
    const unsigned short* __restrict__ Er_bf,
    unsigned char* __restrict__ Gp8) {
  const int n0 = blockIdx.x * 64;
  const int jq = blockIdx.y;       // 0..3
  const int bhl = blockIdx.z;
  const int tid = threadIdx.x, l = tid & 63, w = tid >> 6;
  const int grp = l >> 4, col = l & 15;
  const int jw = jq * 256 + w * 64;
  unsigned char* gbh = Gp8 + (size_t)bhl * GSTRIDE;

  short8 aq[4][2];
#pragma unroll
  for (int rf = 0; rf < 4; ++rf)
#pragma unroll
    for (int dc = 0; dc < 2; ++dc)
      aq[rf][dc] = *(const short8*)(qb + ((size_t)bhl * SEQ + n0 + rf * 16 + col) * HD + dc * 32 + grp * 8);

  f32x4 acc[4][4];
#pragma unroll
  for (int rf = 0; rf < 4; ++rf)
#pragma unroll
    for (int cf = 0; cf < 4; ++cf) acc[rf][cf] = (f32x4){0.f, 0.f, 0.f, 0.f};

#pragma unroll
  for (int cf = 0; cf < 4; ++cf)
#pragma unroll
    for (int dc = 0; dc < 2; ++dc) {
      short8 bfrag = *(const short8*)(Er_bf + (size_t)(jw + cf * 16 + col) * HD + dc * 32 + grp * 8);
#pragma unroll
      for (int rf = 0; rf < 4; ++rf)
        acc[rf][cf] = __builtin_amdgcn_mfma_f32_16x16x32_bf16(aq[rf][dc], bfrag, acc[rf][cf], 0, 0, 0);
    }

#pragma unroll
  for (int rf = 0; rf < 4; ++rf)
#pragma unroll
    for (int cf = 0; cf < 4; ++cf)
#pragma unroll
      for (int rr = 0; rr < 4; ++rr) {
        int n = n0 + rf * 16 + grp * 4 + rr;
        int j = jw + cf * 16 + col;
        float t = acc[rf][cf][rr] * 64.0f;
        t = fminf(fmaxf(t, -120.0f), 120.0f);
        int vi = (int)rintf(t);
        gbh[(size_t)n * GROW + j + 1] = (unsigned char)(vi + 128);
      }
  if (jq == 3 && tid < 64) {
    int n = n0 + tid;
    gbh[(size_t)n * GROW + 1025] = 128;  // skew hole -> 0.0
  }
}

// ---------------- flash attention: QBLK=128, int8 band, P overlaid, stride-144 rows ----------------
// BandP row stride 144 B (36 dwords, rows offset 4 banks — r17's 128-B stride was 33.5M
// conflict cycles). Band bytes [0,64); P (128 B bf16) overlays the same rows.
// STAGE_BAND iterates window starts at multiples of 63 (63 = 7*9 == 0 mod 9) so LANE 0
// IS ACTIVE in every masked global_load_lds — the HW takes the LDS base from the first
// ACTIVE lane and writes lane i at base + i*16, so a masked-off lane 0 shifts the whole
// instruction's writes (r18 failure, absmax 6.25e-2). Overlapping windows rewrite
// identical bytes (benign). Barrier A before the async STAGE_BAND (r12/13 lesson).
// Exact rescale. Grid 8 x 128 = 1024 blocks.
__global__ __launch_bounds__(256) void attn_kernel(
    const unsigned short* __restrict__ qb, const unsigned short* __restrict__ ksw,
    const unsigned short* __restrict__ vtsw, const unsigned char* __restrict__ Gp8,
    unsigned short* __restrict__ attn_o) {
  __shared__ __align__(16) unsigned short KsL[2][4096];
  __shared__ __align__(16) unsigned short VtL[2][4096];
  __shared__ __align__(16) unsigned char BandP[128][144];  // band [0,64) ∪ P bf16 [0,128)

  const int wg = blockIdx.x + 8 * blockIdx.y;
  const int chunk = gridDim.y;  // 128
  const int nid = (wg & 7) * chunk + (wg >> 3);
  const int bhl = nid >> 3;
  const int n0 = (nid & 7) * 128;
  const int b = bhl >> 4, h = bhl & 15;
  const int tid = threadIdx.x, lane = tid & 63, wq = tid >> 6;
  const int grp = lane >> 4, col = lane & 15;

  short8 aq[2][2];
#pragma unroll
  for (int nf = 0; nf < 2; ++nf)
#pragma unroll
    for (int dc = 0; dc < 2; ++dc)
      aq[nf][dc] = *(const short8*)(qb + ((size_t)(bhl * SEQ + n0 + wq * 32 + nf * 16 + col)) * HD + dc * 32 + grp * 8);

  f32x4 acco[2][4];
#pragma unroll
  for (int nf = 0; nf < 2; ++nf)
#pragma unroll
    for (int oc = 0; oc < 4; ++oc) acco[nf][oc] = (f32x4){0.f, 0.f, 0.f, 0.f};
  float mrun[2] = {-INFINITY, -INFINITY}, lrun[2] = {0.f, 0.f};

  const float scale2 = 0.125f * LOG2E;
  const unsigned short* kbh = ksw + (size_t)bhl * SEQ * HD;
  const unsigned short* vbh = vtsw + (size_t)bhl * HD * SEQ;
  // band window start for row r at tile m0: Gp8 + bhl*GSTRIDE + (n0+1+r)*1024 + m0
  const unsigned char* gb0 = Gp8 + (size_t)bhl * GSTRIDE + ((size_t)n0 + 1) * 1024;

  auto STAGE_KV = [&](int buf, int m0) {
#pragma unroll
    for (int i = 0; i < 2; ++i) {
      int gi = i * 256 + wq * 64 + lane;
      int row = gi >> 3, gc = gi & 7;
      gload_lds16(kbh + (((size_t)(m0 + row)) << 6) + gc * 8,
                  &KsL[buf][(i * 256 + wq * 64) * 8]);
      gload_lds16(vbh + (((size_t)row) << 10) + m0 + gc * 8,
                  &VtL[buf][(i * 256 + wq * 64) * 8]);
    }
  };
  auto STAGE_BAND = [&](int m0) {  // 9 slots/row enum; stage sd<4; lane-0-active windows
    const unsigned char* gsrc = gb0 + m0;
    unsigned char* bdst = &BandP[0][0];
    const int g0 = wq * 288;  // wave wq owns rows [wq*32, +32) = 288 slots
#pragma unroll
    for (int it = 0; it < 5; ++it) {
      int g = g0 + it * 63 + lane;  // it*63 % 9 == 0 -> lane 0 has sd=0 (active)
      int r = g / 9, sd = g - r * 9;
      if (sd < 4 && g < g0 + 288)
        gload_lds16(gsrc + (size_t)r * 1024 + sd * 16, bdst + g * 16);
    }
  };

  STAGE_KV(0, 0);
  STAGE_BAND(0);
  __syncthreads();

  for (int t = 0; t < 16; ++t) {
    const int cur = t & 1;
    if (t < 15) STAGE_KV(cur ^ 1, (t + 1) * 64);
    // QK^T swapped
    f32x4 acc[2][4];
#pragma unroll
    for (int nf = 0; nf < 2; ++nf)
#pragma unroll
      for (int mc = 0; mc < 4; ++mc) acc[nf][mc] = (f32x4){0.f, 0.f, 0.f, 0.f};
    __builtin_amdgcn_s_setprio(1);
#pragma unroll
    for (int mc = 0; mc < 4; ++mc)
#pragma unroll
      for (int dc = 0; dc < 2; ++dc) {
        short8 bk = *(const short8*)&KsL[cur][(mc * 16 + col) * 64 + (((dc * 4 + grp) ^ (col & 7)) << 3)];
#pragma unroll
        for (int nf = 0; nf < 2; ++nf)
          acc[nf][mc] = __builtin_amdgcn_mfma_f32_16x16x32_bf16(bk, aq[nf][dc], acc[nf][mc], 0, 0, 0);
      }
    __builtin_amdgcn_s_setprio(0);
    // lane-local online softmax (log2 domain, EXACT rescale); int8 band decode
#pragma unroll
    for (int nf = 0; nf < 2; ++nf) {
      const int dr = wq * 32 + nf * 16 + col;
      float s[4][4];
#pragma unroll
      for (int mc = 0; mc < 4; ++mc) {
        unsigned wrd = *(const unsigned*)&BandP[dr][mc * 16 + grp * 4];
#pragma unroll
        for (int r = 0; r < 4; ++r) {
          float ubf = (float)((wrd >> (8 * r)) & 0xffu);   // -> v_cvt_f32_ubyteN
          s[mc][r] = fmaf(ubf, 0.015625f, fmaf(acc[nf][mc][r], scale2, -2.0f));
        }
      }
      float mx = s[0][0];
#pragma unroll
      for (int mc = 0; mc < 4; ++mc)
#pragma unroll
        for (int r = 0; r < 4; ++r) mx = fmaxf(mx, s[mc][r]);
      mx = fmaxf(mx, __shfl_xor(mx, 16));
      mx = fmaxf(mx, __shfl_xor(mx, 32));
      if (mx > mrun[nf]) {  // exact: keep P <= 1 (bf16 precision budget)
        float cr = hexp2(mrun[nf] - mx);
        mrun[nf] = mx;
        lrun[nf] *= cr;
#pragma unroll
        for (int oc = 0; oc < 4; ++oc)
#pragma unroll
          for (int r = 0; r < 4; ++r) acco[nf][oc][r] *= cr;
      }
      float p[4][4];
#pragma unroll
      for (int mc = 0; mc < 4; ++mc)
#pragma unroll
        for (int r = 0; r < 4; ++r) {
          p[mc][r] = hexp2(s[mc][r] - mrun[nf]);
          lrun[nf] += p[mc][r];
        }
      unsigned int wpk[8];
#pragma unroll
      for (int r = 0; r < 4; ++r)
#pragma unroll
        for (int mh = 0; mh < 2; ++mh)
          asm("v_cvt_pk_bf16_f32 %0, %1, %2"
              : "=v"(wpk[r * 2 + mh]) : "v"(p[mh * 2][r]), "v"(p[mh * 2 + 1][r]));
      *(u32x4*)&BandP[dr][grp * 32] = (u32x4){wpk[0], wpk[1], wpk[2], wpk[3]};
      *(u32x4*)&BandP[dr][grp * 32 + 16] = (u32x4){wpk[4], wpk[5], wpk[6], wpk[7]};
    }
    // hoist ap fragments to regs (same-wave DS, safe without barrier)
    short8 ap[2][2];
#pragma unroll
    for (int nf = 0; nf < 2; ++nf)
#pragma unroll
      for (int kc = 0; kc < 2; ++kc)
        ap[nf][kc] = *(const short8*)&BandP[wq * 32 + nf * 16 + col][kc * 64 + grp * 16];
    __syncthreads();  // A: DS drain — all BandP reads done before async overwrite
    if (t < 15) STAGE_BAND((t + 1) * 64);  // latency hides under PV
    // PV swapped (sigma k-order on both operands)
    __builtin_amdgcn_s_setprio(1);
#pragma unroll
    for (int oc = 0; oc < 4; ++oc)
#pragma unroll
      for (int kc = 0; kc < 2; ++kc) {
        short8 bv = *(const short8*)&VtL[cur][(oc * 16 + col) * 64 + (((kc * 4 + grp) ^ (col & 7)) << 3)];
#pragma unroll
        for (int nf = 0; nf < 2; ++nf)
          acco[nf][oc] = __builtin_amdgcn_mfma_f32_16x16x32_bf16(bv, ap[nf][kc], acco[nf][oc], 0, 0, 0);
      }
    __builtin_amdgcn_s_setprio(0);
    __syncthreads();  // B: drains KV + Band prefetches; protects buf reuse
  }
  // epilogue
#pragma unroll
  for (int nf = 0; nf < 2; ++nf) {
    float tot = lrun[nf];
    tot += __shfl_xor(tot, 16);
    tot += __shfl_xor(tot, 32);
    float inv = 1.0f / tot;
    const int n = n0 + wq * 32 + nf * 16 + col;
#pragma unroll
    for (int oc = 0; oc < 4; ++oc) {
      us4 pk;
#pragma unroll
      for (int r = 0; r < 4; ++r) pk[r] = f2bf(acco[nf][oc][r] * inv);
      *(us4*)&attn_o[((size_t)(b * SEQ + n)) * CH + h * HD + oc * 16 + grp * 4] = pk;
    }
  }
}

extern "C" void kernel_launch(void* const* d_in, const int* in_sizes, int n_in,
                              void* d_out, int out_size, void* d_ws, size_t ws_size,
                              hipStream_t stream) {
  const float* x        = (const float*)d_in[0];
  const float* time_emb = (const float*)d_in[1];
  const float* W_qkv    = (const float*)d_in[2];
  const float* b_qkv    = (const float*)d_in[3];
  const float* W_time   = (const float*)d_in[4];
  const float* b_time   = (const float*)d_in[5];
  const float* W_out    = (const float*)d_in[6];
  const float* b_out    = (const float*)d_in[7];
  const float* Er       = (const float*)d_in[8];
  float* out = (float*)d_out;

  char* p = (char*)d_ws;
  float* tqkv = (float*)p;                      p += 98304;
  unsigned short* qb = (unsigned short*)p;      p += 16777216;
  unsigned short* ksw = (unsigned short*)p;     p += 16777216;
  unsigned short* vtsw = (unsigned short*)p;    p += 16777216;
  unsigned short* attn_o = (unsigned short*)p;  p += 16777216;
  unsigned short* Er_bf = (unsigned short*)p;   p += 131072;
  unsigned short* Wout_t = (unsigned short*)p;  p += 2097152;
  unsigned short* x_bf = (unsigned short*)p;               // 16 MB (prep, then dead)
  unsigned short* Wqkv_t = x_bf + (size_t)8388608;         // 6 MB (prep, then dead)
  unsigned char* Gp8 = (unsigned char*)p;                  // 128 x GSTRIDE = 134.35 MB

  er_convert_kernel<<<256, 256, 0, stream>>>(Er, Er_bf);
  time_proj_kernel<<<96, 256, 0, stream>>>(time_emb, W_time, b_time, tqkv);
  convert_bf_kernel<<<4096, 256, 0, stream>>>(x, x_bf, 1048576);
  transpose_bf_kernel<<<dim3(48, 16), 256, 0, stream>>>(W_qkv, Wqkv_t, 1024, 3072);
  transpose_bf_kernel<<<dim3(16, 16), 256, 0, stream>>>(W_out, Wout_t, 1024, 1024);
  qkv_gemm_w<0><<<dim3(64, 8), 256, 0, stream>>>(x_bf, Wqkv_t, b_qkv, tqkv, qb);
  qkv_gemm_w<1><<<dim3(64, 8), 256, 0, stream>>>(x_bf, Wqkv_t + (size_t)1048576,
                                                 b_qkv + 1024, tqkv + 1024, ksw);
  qkv_gemm_w<2><<<dim3(64, 8), 256, 0, stream>>>(x_bf, Wqkv_t + (size_t)2097152,
                                                 b_qkv + 2048, tqkv + 2048, vtsw);
  g_gemm8<<<dim3(16, 4, 128), 256, 0, stream>>>(qb, Er_bf, Gp8);
  attn_kernel<<<dim3(8, 128), 256, 0, stream>>>(qb, ksw, vtsw, Gp8, attn_o);
  out_gemm_mfma<<<dim3(64, 8), 256, 0, stream>>>(attn_o, Wout_t, b_out, out);
}

// Round 20
// 316.097 us; speedup vs baseline: 1.1705x; 1.0078x over previous
//
#include <hip/hip_runtime.h>
#include <math.h>

typedef __attribute__((ext_vector_type(8))) short short8;
typedef __attribute__((ext_vector_type(8))) unsigned short ushort8;
typedef __attribute__((ext_vector_type(4))) unsigned short us4;
typedef __attribute__((ext_vector_type(4))) unsigned int u32x4;
typedef __attribute__((ext_vector_type(4))) float f32x4;

#define NH 16
#define HD 64
#define SEQ 1024
#define NB 8
#define CH 1024
#define TD 256
#define GROW 1025          // flat row stride of G' (the skew trick; must be exactly 1025)
#define GSTRIDE 1049616    // per-bh byte stride: 1024*1025 + OFS(1) + tail pad, 16-mult
#define LOG2E 1.4426950408889634f

__device__ __forceinline__ unsigned short f2bf(float f) {
  union { float f; unsigned int u; } v; v.f = f;
  unsigned int r = v.u + 0x7FFFu + ((v.u >> 16) & 1u);
  return (unsigned short)(r >> 16);
}
__device__ __forceinline__ float bf2f(unsigned short s) {
  union { unsigned int u; float f; } v; v.u = ((unsigned int)s) << 16;
  return v.f;
}
__device__ __forceinline__ float hexp2(float x) {
  float r;
  asm("v_exp_f32 %0, %1" : "=v"(r) : "v"(x));
  return r;
}
__device__ __forceinline__ void gload_lds16(const void* g, void* l) {
  __builtin_amdgcn_global_load_lds(
      (const __attribute__((address_space(1))) unsigned int*)g,
      (__attribute__((address_space(3))) unsigned int*)l, 16, 0, 0);
}

// ---------------- time projection (fp32) ----------------
__global__ __launch_bounds__(256) void time_proj_kernel(
    const float* __restrict__ time_emb, const float* __restrict__ W_time,
    const float* __restrict__ b_time, float* __restrict__ tqkv) {
  int idx = blockIdx.x * 256 + threadIdx.x;
  if (idx >= NB * 3072) return;
  int b = idx / 3072, c = idx % 3072;
  float s = b_time[c];
  for (int t = 0; t < TD; ++t) s += time_emb[b * TD + t] * W_time[t * 3072 + c];
  tqkv[idx] = s;
}

// ---------------- Er fp32 -> bf16, scaled by log2e ----------------
__global__ __launch_bounds__(256) void er_convert_kernel(
    const float* __restrict__ Er, unsigned short* __restrict__ Er_bf) {
  int i = blockIdx.x * 256 + threadIdx.x;
  if (i < SEQ * HD) Er_bf[i] = f2bf(Er[i] * LOG2E);
}

// ---------------- fp32 -> bf16 vector convert ----------------
__global__ __launch_bounds__(256) void convert_bf_kernel(
    const float* __restrict__ in, unsigned short* __restrict__ out, int n8) {
  int i = blockIdx.x * 256 + threadIdx.x;
  if (i >= n8) return;
  float4 a = ((const float4*)in)[2 * i];
  float4 b = ((const float4*)in)[2 * i + 1];
  ushort8 o;
  o[0] = f2bf(a.x); o[1] = f2bf(a.y); o[2] = f2bf(a.z); o[3] = f2bf(a.w);
  o[4] = f2bf(b.x); o[5] = f2bf(b.y); o[6] = f2bf(b.z); o[7] = f2bf(b.w);
  ((ushort8*)out)[i] = o;
}

// ---------------- fp32 W[R][C] -> bf16 Wt[C][R] ----------------
__global__ __launch_bounds__(256) void transpose_bf_kernel(
    const float* __restrict__ W, unsigned short* __restrict__ Wt, int R, int Cc) {
  __shared__ float T[64][65];
  int r0 = blockIdx.y * 64, c0 = blockIdx.x * 64;
  for (int idx = threadIdx.x; idx < 4096; idx += 256) {
    int r = idx >> 6, c = idx & 63;
    T[r][c] = W[(size_t)(r0 + r) * Cc + c0 + c];
  }
  __syncthreads();
  for (int idx = threadIdx.x; idx < 4096; idx += 256) {
    int c = idx >> 6, r = idx & 63;
    Wt[(size_t)(c0 + c) * R + r0 + r] = f2bf(T[r][c]);
  }
}

// ---------------- QKV GEMM: bf16 MFMA, WHICH-specialized epilogue ----------------
template <int WHICH>
__global__ __launch_bounds__(256) void qkv_gemm_w(
    const unsigned short* __restrict__ A, const unsigned short* __restrict__ Bt,
    const float* __restrict__ bq, const float* __restrict__ tq,
    unsigned short* __restrict__ dst) {
  __shared__ unsigned short As[128 * 32];
  __shared__ unsigned short Bs[128 * 32];
  const int m0 = blockIdx.x * 128, n0 = blockIdx.y * 128;
  const int tid = threadIdx.x, l = tid & 63, w = tid >> 6;
  const int wm = w >> 1, wn = w & 1;
  const int grp = l >> 4, col = l & 15;
  f32x4 acc[4][4];
#pragma unroll
  for (int mi = 0; mi < 4; ++mi)
#pragma unroll
    for (int ni = 0; ni < 4; ++ni) acc[mi][ni] = (f32x4){0.f, 0.f, 0.f, 0.f};

  for (int k0 = 0; k0 < 1024; k0 += 32) {
    __syncthreads();
#pragma unroll
    for (int i = 0; i < 2; ++i) {
      int seg = i * 256 + w * 64 + l;
      int mr = seg >> 2, kq = seg & 3;
      gload_lds16(A + (size_t)(m0 + mr) * 1024 + k0 + kq * 8,
                  &As[(i * 256 + w * 64) * 8]);
      gload_lds16(Bt + (size_t)(n0 + mr) * 1024 + k0 + kq * 8,
                  &Bs[(i * 256 + w * 64) * 8]);
    }
    __syncthreads();
    short8 af[4], bfv[4];
#pragma unroll
    for (int mi = 0; mi < 4; ++mi)
      af[mi] = *(const short8*)&As[(wm * 64 + mi * 16 + col) * 32 + grp * 8];
#pragma unroll
    for (int ni = 0; ni < 4; ++ni)
      bfv[ni] = *(const short8*)&Bs[(wn * 64 + ni * 16 + col) * 32 + grp * 8];
#pragma unroll
    for (int mi = 0; mi < 4; ++mi)
#pragma unroll
      for (int ni = 0; ni < 4; ++ni)
        acc[mi][ni] = __builtin_amdgcn_mfma_f32_16x16x32_bf16(af[mi], bfv[ni], acc[mi][ni], 0, 0, 0);
  }

  const int bidx = m0 >> 10;
  float biasv[4];
  int hhv[4], dv[4];
#pragma unroll
  for (int ni = 0; ni < 4; ++ni) {
    int c2 = n0 + wn * 64 + ni * 16 + col;
    biasv[ni] = bq[c2] + tq[bidx * 3072 + c2];
    hhv[ni] = c2 >> 6;
    dv[ni] = c2 & 63;
  }
  if (WHICH == 2) {
    int t = (m0 & 1023) + wm * 64;
#pragma unroll
    for (int ni = 0; ni < 4; ++ni) {
      size_t rowb = ((size_t)(bidx * 16 + hhv[ni]) * 64 + dv[ni]) * 1024;
      int swz = (dv[ni] & 7) << 3;
#pragma unroll
      for (int rr = 0; rr < 4; ++rr) {
        int kbase = (grp * 4 + rr) * 4;
        int colix = t + ((kbase & ~7) ^ swz) + (kbase & 7);
        us4 pk;
#pragma unroll
        for (int mi = 0; mi < 4; ++mi) pk[mi] = f2bf(acc[mi][ni][rr] + biasv[ni]);
        *(us4*)&dst[rowb + colix] = pk;
      }
    }
  } else if (WHICH == 1) {
#pragma unroll
    for (int mi = 0; mi < 4; ++mi)
#pragma unroll
      for (int rr = 0; rr < 4; ++rr) {
        int nn = (m0 + wm * 64 + mi * 16 + grp * 4 + rr) & 1023;
#pragma unroll
        for (int ni = 0; ni < 4; ++ni) {
          size_t bhh = (size_t)(bidx * 16 + hhv[ni]);
          dst[(bhh * 1024 + nn) * 64 + (dv[ni] ^ ((nn & 7) << 3))] =
              f2bf(acc[mi][ni][rr] + biasv[ni]);
        }
      }
  } else {
#pragma unroll
    for (int mi = 0; mi < 4; ++mi)
#pragma unroll
      for (int rr = 0; rr < 4; ++rr) {
        int nn = (m0 + wm * 64 + mi * 16 + grp * 4 + rr) & 1023;
#pragma unroll
        for (int ni = 0; ni < 4; ++ni) {
          size_t bhh = (size_t)(bidx * 16 + hhv[ni]);
          dst[(bhh * 1024 + nn) * 64 + dv[ni]] = f2bf(acc[mi][ni][rr] + biasv[ni]);
        }
      }
  }
}

// ---------------- output projection: bf16 MFMA ----------------
__global__ __launch_bounds__(256) void out_gemm_mfma(
    const unsigned short* __restrict__ A, const unsigned short* __restrict__ Bt,
    const float* __restrict__ bias, float* __restrict__ out) {
  __shared__ unsigned short As[128 * 32];
  __shared__ unsigned short Bs[128 * 32];
  const int m0 = blockIdx.x * 128, n0 = blockIdx.y * 128;
  const int tid = threadIdx.x, l = tid & 63, w = tid >> 6;
  const int wm = w >> 1, wn = w & 1;
  const int grp = l >> 4, col = l & 15;
  f32x4 acc[4][4];
#pragma unroll
  for (int mi = 0; mi < 4; ++mi)
#pragma unroll
    for (int ni = 0; ni < 4; ++ni) acc[mi][ni] = (f32x4){0.f, 0.f, 0.f, 0.f};

  for (int k0 = 0; k0 < 1024; k0 += 32) {
    __syncthreads();
#pragma unroll
    for (int i = 0; i < 2; ++i) {
      int seg = i * 256 + w * 64 + l;
      int mr = seg >> 2, kq = seg & 3;
      gload_lds16(A + (size_t)(m0 + mr) * 1024 + k0 + kq * 8,
                  &As[(i * 256 + w * 64) * 8]);
      gload_lds16(Bt + (size_t)(n0 + mr) * 1024 + k0 + kq * 8,
                  &Bs[(i * 256 + w * 64) * 8]);
    }
    __syncthreads();
    short8 af[4], bfv[4];
#pragma unroll
    for (int mi = 0; mi < 4; ++mi)
      af[mi] = *(const short8*)&As[(wm * 64 + mi * 16 + col) * 32 + grp * 8];
#pragma unroll
    for (int ni = 0; ni < 4; ++ni)
      bfv[ni] = *(const short8*)&Bs[(wn * 64 + ni * 16 + col) * 32 + grp * 8];
#pragma unroll
    for (int mi = 0; mi < 4; ++mi)
#pragma unroll
      for (int ni = 0; ni < 4; ++ni)
        acc[mi][ni] = __builtin_amdgcn_mfma_f32_16x16x32_bf16(af[mi], bfv[ni], acc[mi][ni], 0, 0, 0);
  }
  float bv[4];
#pragma unroll
  for (int ni = 0; ni < 4; ++ni) bv[ni] = bias[n0 + wn * 64 + ni * 16 + col];
#pragma unroll
  for (int mi = 0; mi < 4; ++mi)
#pragma unroll
    for (int rr = 0; rr < 4; ++rr) {
      int row = m0 + wm * 64 + mi * 16 + grp * 4 + rr;
#pragma unroll
      for (int ni = 0; ni < 4; ++ni) {
        int c = n0 + wn * 64 + ni * 16 + col;
        out[(size_t)row * 1024 + c] = acc[mi][ni][rr] + bv[ni];
      }
    }
}

// ---------------- G' GEMM -> int8 (biased ubyte, scale 1/64), +1 byte offset ----------------
// Gp8[bh*GSTRIDE + n*1025 + j + 1] = round(G'[n][j]*64)+128; skew hole (j=1024) = 128 (0.0).
// +1 offset makes every attn band window start 16B-aligned (1024 == 0 mod 16).
__global__ __launch_bounds__(256) void g_gemm8(
    const unsigned short* __restrict__ qb,
    const unsigned short* __restrict__ Er_bf,
    unsigned char* __restrict__ Gp8) {
  const int n0 = blockIdx.x * 64;
  const int jq = blockIdx.y;       // 0..3
  const int bhl = blockIdx.z;
  const int tid = threadIdx.x, l = tid & 63, w = tid >> 6;
  const int grp = l >> 4, col = l & 15;
  const int jw = jq * 256 + w * 64;
  unsigned char* gbh = Gp8 + (size_t)bhl * GSTRIDE;

  short8 aq[4][2];
#pragma unroll
  for (int rf = 0; rf < 4; ++rf)
#pragma unroll
    for (int dc = 0; dc < 2; ++dc)
      aq[rf][dc] = *(const short8*)(qb + ((size_t)bhl * SEQ + n0 + rf * 16 + col) * HD + dc * 32 + grp * 8);

  f32x4 acc[4][4];
#pragma unroll
  for (int rf = 0; rf < 4; ++rf)
#pragma unroll
    for (int cf = 0; cf < 4; ++cf) acc[rf][cf] = (f32x4){0.f, 0.f, 0.f, 0.f};

#pragma unroll
  for (int cf = 0; cf < 4; ++cf)
#pragma unroll
    for (int dc = 0; dc < 2; ++dc) {
      short8 bfrag = *(const short8*)(Er_bf + (size_t)(jw + cf * 16 + col) * HD + dc * 32 + grp * 8);
#pragma unroll
      for (int rf = 0; rf < 4; ++rf)
        acc[rf][cf] = __builtin_amdgcn_mfma_f32_16x16x32_bf16(aq[rf][dc], bfrag, acc[rf][cf], 0, 0, 0);
    }

#pragma unroll
  for (int rf = 0; rf < 4; ++rf)
#pragma unroll
    for (int cf = 0; cf < 4; ++cf)
#pragma unroll
      for (int rr = 0; rr < 4; ++rr) {
        int n = n0 + rf * 16 + grp * 4 + rr;
        int j = jw + cf * 16 + col;
        float t = acc[rf][cf][rr] * 64.0f;
        t = fminf(fmaxf(t, -120.0f), 120.0f);
        int vi = (int)rintf(t);
        gbh[(size_t)n * GROW + j + 1] = (unsigned char)(vi + 128);
      }
  if (jq == 3 && tid < 64) {
    int n = n0 + tid;
    gbh[(size_t)n * GROW + 1025] = 128;  // skew hole -> 0.0
  }
}

// ---------------- flash attention: QBLK=128, int8 band DOUBLE-buffered, 1 barrier/step ----------------
// Band rows are WAVE-PRIVATE -> no cross-wave barrier needed for band at all. Double-
// buffering removes the r14 "barrier A": softmax reads BandP[cur], P overlays BandP[cur]
// (consumed; same-lane program order), ap hoisted to regs, then STAGE_BAND(t+1) targets
// BandP[cur^1] — disjoint from every access this step. The single end-of-step barrier
// (vmcnt drain) orders prefetched band/KV writes vs next step's reads (r12/13 lesson:
// global_load_lds's LDS write is unordered with the DS pipe without that drain).
// Row stride 144 B (rows offset 4 banks; 128-B stride was 33.5M conflict cycles in r17).
// STAGE_BAND windows start at multiples of 63 (== 0 mod 9) so LANE 0 IS ACTIVE in every
// masked global_load_lds (HW takes the LDS base from the first ACTIVE lane; a masked-off
// lane 0 shifts the whole instruction's writes — r18 failure). Exact rescale (defer-max
// broke the absmax budget in r12). Grid 8 x 128 = 1024 blocks.
__global__ __launch_bounds__(256) void attn_kernel(
    const unsigned short* __restrict__ qb, const unsigned short* __restrict__ ksw,
    const unsigned short* __restrict__ vtsw, const unsigned char* __restrict__ Gp8,
    unsigned short* __restrict__ attn_o) {
  __shared__ __align__(16) unsigned short KsL[2][4096];
  __shared__ __align__(16) unsigned short VtL[2][4096];
  __shared__ __align__(16) unsigned char BandP[2][128][144];  // band [0,64) ∪ P bf16 [0,128)

  const int wg = blockIdx.x + 8 * blockIdx.y;
  const int chunk = gridDim.y;  // 128
  const int nid = (wg & 7) * chunk + (wg >> 3);
  const int bhl = nid >> 3;
  const int n0 = (nid & 7) * 128;
  const int b = bhl >> 4, h = bhl & 15;
  const int tid = threadIdx.x, lane = tid & 63, wq = tid >> 6;
  const int grp = lane >> 4, col = lane & 15;

  short8 aq[2][2];
#pragma unroll
  for (int nf = 0; nf < 2; ++nf)
#pragma unroll
    for (int dc = 0; dc < 2; ++dc)
      aq[nf][dc] = *(const short8*)(qb + ((size_t)(bhl * SEQ + n0 + wq * 32 + nf * 16 + col)) * HD + dc * 32 + grp * 8);

  f32x4 acco[2][4];
#pragma unroll
  for (int nf = 0; nf < 2; ++nf)
#pragma unroll
    for (int oc = 0; oc < 4; ++oc) acco[nf][oc] = (f32x4){0.f, 0.f, 0.f, 0.f};
  float mrun[2] = {-INFINITY, -INFINITY}, lrun[2] = {0.f, 0.f};

  const float scale2 = 0.125f * LOG2E;
  const unsigned short* kbh = ksw + (size_t)bhl * SEQ * HD;
  const unsigned short* vbh = vtsw + (size_t)bhl * HD * SEQ;
  // band window start for row r at tile m0: Gp8 + bhl*GSTRIDE + (n0+1+r)*1024 + m0
  const unsigned char* gb0 = Gp8 + (size_t)bhl * GSTRIDE + ((size_t)n0 + 1) * 1024;

  auto STAGE_KV = [&](int buf, int m0) {
#pragma unroll
    for (int i = 0; i < 2; ++i) {
      int gi = i * 256 + wq * 64 + lane;
      int row = gi >> 3, gc = gi & 7;
      gload_lds16(kbh + (((size_t)(m0 + row)) << 6) + gc * 8,
                  &KsL[buf][(i * 256 + wq * 64) * 8]);
      gload_lds16(vbh + (((size_t)row) << 10) + m0 + gc * 8,
                  &VtL[buf][(i * 256 + wq * 64) * 8]);
    }
  };
  auto STAGE_BAND = [&](int buf, int m0) {  // 9 slots/row enum; sd<4; lane-0-active windows
    const unsigned char* gsrc = gb0 + m0;
    unsigned char* bdst = &BandP[buf][0][0];
    const int g0 = wq * 288;  // wave wq owns rows [wq*32, +32) = 288 slots
#pragma unroll
    for (int it = 0; it < 5; ++it) {
      int g = g0 + it * 63 + lane;  // it*63 % 9 == 0 -> lane 0 has sd=0 (active)
      int r = g / 9, sd = g - r * 9;
      if (sd < 4 && g < g0 + 288)
        gload_lds16(gsrc + (size_t)r * 1024 + sd * 16, bdst + g * 16);
    }
  };

  STAGE_KV(0, 0);
  STAGE_BAND(0, 0);
  __syncthreads();

  for (int t = 0; t < 16; ++t) {
    const int cur = t & 1;
    if (t < 15) STAGE_KV(cur ^ 1, (t + 1) * 64);
    // QK^T swapped
    f32x4 acc[2][4];
#pragma unroll
    for (int nf = 0; nf < 2; ++nf)
#pragma unroll
      for (int mc = 0; mc < 4; ++mc) acc[nf][mc] = (f32x4){0.f, 0.f, 0.f, 0.f};
    __builtin_amdgcn_s_setprio(1);
#pragma unroll
    for (int mc = 0; mc < 4; ++mc)
#pragma unroll
      for (int dc = 0; dc < 2; ++dc) {
        short8 bk = *(const short8*)&KsL[cur][(mc * 16 + col) * 64 + (((dc * 4 + grp) ^ (col & 7)) << 3)];
#pragma unroll
        for (int nf = 0; nf < 2; ++nf)
          acc[nf][mc] = __builtin_amdgcn_mfma_f32_16x16x32_bf16(bk, aq[nf][dc], acc[nf][mc], 0, 0, 0);
      }
    __builtin_amdgcn_s_setprio(0);
    // lane-local online softmax (log2 domain, EXACT rescale); int8 band decode;
    // P overwrites BandP[cur] (this buffer is fully consumed this step)
#pragma unroll
    for (int nf = 0; nf < 2; ++nf) {
      const int dr = wq * 32 + nf * 16 + col;
      float s[4][4];
#pragma unroll
      for (int mc = 0; mc < 4; ++mc) {
        unsigned wrd = *(const unsigned*)&BandP[cur][dr][mc * 16 + grp * 4];
#pragma unroll
        for (int r = 0; r < 4; ++r) {
          float ubf = (float)((wrd >> (8 * r)) & 0xffu);   // -> v_cvt_f32_ubyteN
          s[mc][r] = fmaf(ubf, 0.015625f, fmaf(acc[nf][mc][r], scale2, -2.0f));
        }
      }
      float mx = s[0][0];
#pragma unroll
      for (int mc = 0; mc < 4; ++mc)
#pragma unroll
        for (int r = 0; r < 4; ++r) mx = fmaxf(mx, s[mc][r]);
      mx = fmaxf(mx, __shfl_xor(mx, 16));
      mx = fmaxf(mx, __shfl_xor(mx, 32));
      if (mx > mrun[nf]) {  // exact: keep P <= 1 (bf16 precision budget)
        float cr = hexp2(mrun[nf] - mx);
        mrun[nf] = mx;
        lrun[nf] *= cr;
#pragma unroll
        for (int oc = 0; oc < 4; ++oc)
#pragma unroll
          for (int r = 0; r < 4; ++r) acco[nf][oc][r] *= cr;
      }
      float p[4][4];
#pragma unroll
      for (int mc = 0; mc < 4; ++mc)
#pragma unroll
        for (int r = 0; r < 4; ++r) {
          p[mc][r] = hexp2(s[mc][r] - mrun[nf]);
          lrun[nf] += p[mc][r];
        }
      unsigned int wpk[8];
#pragma unroll
      for (int r = 0; r < 4; ++r)
#pragma unroll
        for (int mh = 0; mh < 2; ++mh)
          asm("v_cvt_pk_bf16_f32 %0, %1, %2"
              : "=v"(wpk[r * 2 + mh]) : "v"(p[mh * 2][r]), "v"(p[mh * 2 + 1][r]));
      *(u32x4*)&BandP[cur][dr][grp * 32] = (u32x4){wpk[0], wpk[1], wpk[2], wpk[3]};
      *(u32x4*)&BandP[cur][dr][grp * 32 + 16] = (u32x4){wpk[4], wpk[5], wpk[6], wpk[7]};
    }
    // hoist ap fragments to regs (same-wave DS, program order)
    short8 ap[2][2];
#pragma unroll
    for (int nf = 0; nf < 2; ++nf)
#pragma unroll
      for (int kc = 0; kc < 2; ++kc)
        ap[nf][kc] = *(const short8*)&BandP[cur][wq * 32 + nf * 16 + col][kc * 64 + grp * 16];
    // prefetch next band into the OTHER buffer — disjoint from all accesses this step
    if (t < 15) STAGE_BAND(cur ^ 1, (t + 1) * 64);
    // PV swapped (sigma k-order on both operands)
    __builtin_amdgcn_s_setprio(1);
#pragma unroll
    for (int oc = 0; oc < 4; ++oc)
#pragma unroll
      for (int kc = 0; kc < 2; ++kc) {
        short8 bv = *(const short8*)&VtL[cur][(oc * 16 + col) * 64 + (((kc * 4 + grp) ^ (col & 7)) << 3)];
#pragma unroll
        for (int nf = 0; nf < 2; ++nf)
          acco[nf][oc] = __builtin_amdgcn_mfma_f32_16x16x32_bf16(bv, ap[nf][kc], acco[nf][oc], 0, 0, 0);
      }
    __builtin_amdgcn_s_setprio(0);
    __syncthreads();  // single barrier: drains KV + band prefetches; protects buf reuse
  }
  // epilogue
#pragma unroll
  for (int nf = 0; nf < 2; ++nf) {
    float tot = lrun[nf];
    tot += __shfl_xor(tot, 16);
    tot += __shfl_xor(tot, 32);
    float inv = 1.0f / tot;
    const int n = n0 + wq * 32 + nf * 16 + col;
#pragma unroll
    for (int oc = 0; oc < 4; ++oc) {
      us4 pk;
#pragma unroll
      for (int r = 0; r < 4; ++r) pk[r] = f2bf(acco[nf][oc][r] * inv);
      *(us4*)&attn_o[((size_t)(b * SEQ + n)) * CH + h * HD + oc * 16 + grp * 4] = pk;
    }
  }
}

extern "C" void kernel_launch(void* const* d_in, const int* in_sizes, int n_in,
                              void* d_out, int out_size, void* d_ws, size_t ws_size,
                              hipStream_t stream) {
  const float* x        = (const float*)d_in[0];
  const float* time_emb = (const float*)d_in[1];
  const float* W_qkv    = (const float*)d_in[2];
  const float* b_qkv    = (const float*)d_in[3];
  const float* W_time   = (const float*)d_in[4];
  const float* b_time   = (const float*)d_in[5];
  const float* W_out    = (const float*)d_in[6];
  const float* b_out    = (const float*)d_in[7];
  const float* Er       = (const float*)d_in[8];
  float* out = (float*)d_out;

  char* p = (char*)d_ws;
  float* tqkv = (float*)p;                      p += 98304;
  unsigned short* qb = (unsigned short*)p;      p += 16777216;
  unsigned short* ksw = (unsigned short*)p;     p += 16777216;
  unsigned short* vtsw = (unsigned short*)p;    p += 16777216;
  unsigned short* attn_o = (unsigned short*)p;  p += 16777216;
  unsigned short* Er_bf = (unsigned short*)p;   p += 131072;
  unsigned short* Wout_t = (unsigned short*)p;  p += 2097152;
  unsigned short* x_bf = (unsigned short*)p;               // 16 MB (prep, then dead)
  unsigned short* Wqkv_t = x_bf + (size_t)8388608;         // 6 MB (prep, then dead)
  unsigned char* Gp8 = (unsigned char*)p;                  // 128 x GSTRIDE = 134.35 MB

  er_convert_kernel<<<256, 256, 0, stream>>>(Er, Er_bf);
  time_proj_kernel<<<96, 256, 0, stream>>>(time_emb, W_time, b_time, tqkv);
  convert_bf_kernel<<<4096, 256, 0, stream>>>(x, x_bf, 1048576);
  transpose_bf_kernel<<<dim3(48, 16), 256, 0, stream>>>(W_qkv, Wqkv_t, 1024, 3072);
  transpose_bf_kernel<<<dim3(16, 16), 256, 0, stream>>>(W_out, Wout_t, 1024, 1024);
  qkv_gemm_w<0><<<dim3(64, 8), 256, 0, stream>>>(x_bf, Wqkv_t, b_qkv, tqkv, qb);
  qkv_gemm_w<1><<<dim3(64, 8), 256, 0, stream>>>(x_bf, Wqkv_t + (size_t)1048576,
                                                 b_qkv + 1024, tqkv + 1024, ksw);
  qkv_gemm_w<2><<<dim3(64, 8), 256, 0, stream>>>(x_bf, Wqkv_t + (size_t)2097152,
                                                 b_qkv + 2048, tqkv + 2048, vtsw);
  g_gemm8<<<dim3(16, 4, 128), 256, 0, stream>>>(qb, Er_bf, Gp8);
  attn_kernel<<<dim3(8, 128), 256, 0, stream>>>(qb, ksw, vtsw, Gp8, attn_o);
  out_gemm_mfma<<<dim3(64, 8), 256, 0, stream>>>(attn_o, Wout_t, b_out, out);
}